// Round 12
// baseline (3291.010 us; speedup 1.0000x reference)
//
#include <hip/hip_runtime.h>
#include <hip/hip_bf16.h>
#include <math.h>

#define NRAD 96
#define HIDDIM 128
typedef unsigned short ushortT;

typedef __attribute__((ext_vector_type(8))) short bf8_t;   // 8 bf16 (4 VGPRs)
typedef __attribute__((ext_vector_type(4))) float f4_t;    // 4 fp32 acc
typedef __attribute__((ext_vector_type(2))) float f2_t;    // packed fp32 pair

#if defined(__has_builtin)
#  if __has_builtin(__builtin_amdgcn_global_load_lds)
#    define HAVE_GLDS 1
#  endif
#  if __has_builtin(__builtin_amdgcn_rcpf)
#    define RCPF(x) __builtin_amdgcn_rcpf(x)
#  endif
#  if __has_builtin(__builtin_amdgcn_exp2f)
#    define EXP2F(x) __builtin_amdgcn_exp2f(x)
#  endif
#  if __has_builtin(__builtin_amdgcn_cosf)
#    define COSR(x) __builtin_amdgcn_cosf(x)   /* cos(2*pi*x) */
#  endif
#endif
#ifndef RCPF
#  define RCPF(x) (1.f/(x))
#endif
#ifndef EXP2F
#  define EXP2F(x) exp2f(x)
#endif
#ifndef COSR
#  define COSR(x) cosf(6.2831853071795864f*(x))
#endif
#define LOG2E 1.44269504088896f
#define LN2   0.69314718055995f

__device__ __forceinline__ float silu_f(float x){
  return x * RCPF(1.f + EXP2F(-LOG2E*x));
}
__device__ __forceinline__ float b2f(ushortT u){ return __uint_as_float(((unsigned int)u) << 16); }
__device__ __forceinline__ ushortT f2b(float x){
  unsigned int u = __float_as_uint(x);
  unsigned int r = (u + 0x7fffu + ((u >> 16) & 1u)) >> 16;
  return (ushortT)r;
}

#ifdef HAVE_GLDS
__device__ __forceinline__ void glds16(const ushortT* g, ushortT* l){
  __builtin_amdgcn_global_load_lds(
      (const __attribute__((address_space(1))) ushortT*)g,
      (__attribute__((address_space(3))) ushortT*)l, 16, 0, 0);
}
#endif

// ---------------- dtype detection (parallel) ----------------
__global__ void k_detect(const ushortT* posw, int npos,
                         const int* batchw, int nb, int* flags){
  int tot = (npos < 4096 ? npos : 4096);
  int big = tot > nb ? tot : nb;
  int bad = 0, orv = 0;
  for (int t = blockIdx.x*blockDim.x + threadIdx.x; t < big; t += gridDim.x*blockDim.x){
    if (t < tot){
      float x = b2f(posw[t]);
      if (!(fabsf(x) <= 1000.f)) bad = 1;
    }
    if (t < nb && (t & 1)) orv |= batchw[t];
  }
  if (bad) atomicOr(&flags[2], 1);
  if (orv) atomicOr(&flags[3], 1);
}

__global__ void k_iconv(const int* zsrc, const int* bsrc, const int* esrc,
                        int* zi, int* bi, int* eii, int Nn, int E, const int* flags,
                        int* deg){
  int f = (flags[3] == 0) ? 1 : 0;   // 1 => int64
  int total = 2*Nn + 2*E;
  for (int t = blockIdx.x*blockDim.x + threadIdx.x; t < total; t += gridDim.x*blockDim.x){
    if (t < Nn) zi[t] = zsrc[(size_t)t << f];
    else if (t < 2*Nn) bi[t-Nn] = bsrc[(size_t)(t-Nn) << f];
    else {
      int e = t - 2*Nn;
      int v = esrc[(size_t)e << f];
      eii[e] = v;
      if (e >= E) atomicAdd(&deg[v], 1);
    }
  }
}

// ---------------- conversion: (bf16|f32) -> f32 ----------------
struct ConvDesc { const ushortT* src; float* dst; int n; };
struct ConvArgs { ConvDesc d[32]; };

__global__ void k_conv(ConvArgs a, int cnt, const int* flags){
  int y = blockIdx.y;
  if (y >= cnt) return;
  int f = (flags[2] == 0) ? 1 : 0;    // 1 => bf16
  const ushortT* s = a.d[y].src;
  float* dst = a.d[y].dst;
  int n = a.d[y].n;
  if (f){
    for (int t = blockIdx.x*blockDim.x + threadIdx.x; t < n; t += gridDim.x*blockDim.x)
      dst[t] = b2f(s[t]);
  } else {
    const float* sf = (const float*)s;
    for (int t = blockIdx.x*blockDim.x + threadIdx.x; t < n; t += gridDim.x*blockDim.x)
      dst[t] = sf[t];
  }
}

// prescale l3 weights: [0,96) w1*-log2e, [96,128) b1*-log2e, [128,160) w2*-ln2, [160] b2
__global__ void k_l3pre(const float* __restrict__ w1, const float* __restrict__ b1,
                        const float* __restrict__ w2, const float* __restrict__ b2,
                        float* __restrict__ l3s){
  int t = threadIdx.x;
  if (t < 96) l3s[t] = w1[t] * (-LOG2E);
  else if (t < 128) l3s[t] = b1[t-96] * (-LOG2E);
  else if (t < 160) l3s[t] = w2[t-128] * (-LN2);
  else if (t == 160) l3s[160] = b2[0];
}

// ---------------- weight transpose -> bf16 [N][K] ----------------
struct TDesc { const ushortT* src; ushortT* dst; int K, N; };
struct TArgs { TDesc d[12]; };

__global__ void k_wt(TArgs a, int cnt, const int* flags){
  int y = blockIdx.y;
  if (y >= cnt) return;
  int f = (flags[2] == 0) ? 1 : 0;
  const ushortT* s = a.d[y].src;
  ushortT* dst = a.d[y].dst;
  int K = a.d[y].K, N = a.d[y].N, tot = K*N;
  for (int t = blockIdx.x*blockDim.x + threadIdx.x; t < tot; t += gridDim.x*blockDim.x){
    int k = t / N, n = t - k*N;
    ushortT v = f ? s[t] : f2b(((const float*)s)[t]);
    dst[(size_t)n*K + k] = v;
  }
}

__global__ void k_f2b(const float* __restrict__ src, ushortT* __restrict__ dst, int n){
  for (int t = blockIdx.x*blockDim.x + threadIdx.x; t < n; t += gridDim.x*blockDim.x)
    dst[t] = f2b(src[t]);
}

__global__ void k_zero(float* __restrict__ p, int n){
  int t = blockIdx.x*blockDim.x + threadIdx.x;
  int stride = gridDim.x*blockDim.x;
  for (; t < n; t += stride) p[t] = 0.f;
}

__global__ void k_sentinel(__hip_bfloat16* out, int n, float val){
  int t = threadIdx.x;
  if (t < n) out[t] = __float2bfloat16(val);
}

// ---------------- CSR scan + scatter ----------------
__global__ void k_csr_scan(const int* __restrict__ deg, int* __restrict__ rowptr, int Nn){
  __shared__ int sh[256];
  __shared__ int carry;
  if (threadIdx.x == 0){ carry = 0; rowptr[0] = 0; }
  __syncthreads();
  for (int t0 = 0; t0 < Nn; t0 += 256){
    int idx = t0 + threadIdx.x;
    int v = (idx < Nn) ? deg[idx] : 0;
    sh[threadIdx.x] = v; __syncthreads();
    for (int o = 1; o < 256; o <<= 1){
      int u = (threadIdx.x >= o) ? sh[threadIdx.x - o] : 0;
      __syncthreads();
      sh[threadIdx.x] += u; __syncthreads();
    }
    if (idx < Nn) rowptr[idx + 1] = carry + sh[threadIdx.x];
    __syncthreads();
    if (threadIdx.x == 0) carry += sh[255];
    __syncthreads();
  }
}

__global__ void k_csr_scatter(const int* __restrict__ eii, int E,
                              const int* __restrict__ rowptr, int* __restrict__ cursor,
                              int* __restrict__ jp, int* __restrict__ ip){
  int e = blockIdx.x*blockDim.x + threadIdx.x;
  if (e >= E) return;
  int i = eii[E+e];
  int p = atomicAdd(&cursor[i], 1);
  int k = rowptr[i] + p;
  jp[k] = eii[e];
  ip[k] = i;
}

// ---------------- geometry + RBF ----------------
__global__ void k_geom(const float* __restrict__ pos,
                       const int* __restrict__ jp, const int* __restrict__ ip,
                       int off, int Cc,
                       float* __restrict__ edb, float* __restrict__ ecv,
                       float* __restrict__ rb, ushortT* __restrict__ remb)
{
  int el = blockIdx.x*blockDim.x + threadIdx.x;
  if (el >= Cc) return;
  int g = off + el;
  int j = jp[g], i = ip[g];
  float pjx = pos[3*j], pjy = pos[3*j+1], pjz = pos[3*j+2];
  float pix = pos[3*i], piy = pos[3*i+1], piz = pos[3*i+2];
  float vx = pjx-pix, vy = pjy-piy, vz = pjz-piz;
  float d = sqrtf(vx*vx + vy*vy + vz*vz);
  float inv = RCPF(d + 1e-10f);
  float edx = vx*inv, edy = vy*inv, edz = vz*inv;
  edb[3*el]=edx; edb[3*el+1]=edy; edb[3*el+2]=edz;
  if (ecv){
    float cx = piy*pjz - piz*pjy;
    float cy = piz*pjx - pix*pjz;
    float cz = pix*pjy - piy*pjx;
    float cn = sqrtf(cx*cx + cy*cy + cz*cz);
    float inv2 = RCPF(cn + 1e-10f);
    cx *= inv2; cy *= inv2; cz *= inv2;
    ecv[6*el]=cx; ecv[6*el+1]=cy; ecv[6*el+2]=cz;
    ecv[6*el+3]=edy*cz - edz*cy;
    ecv[6*el+4]=edz*cx - edx*cz;
    ecv[6*el+5]=edx*cy - edy*cx;
  }
  float rbv = 0.5f*(COSR(d*0.08333333333f) + 1.f);   // cos(d*pi/6)
  rb[el] = rbv;
  float env = (d < 6.f) ? rbv : 0.f;
  const float stf = 0.0024787522f;
  const float prf = (2.0f/96.0f)*(1.0f - stf);
  const float betaL = LOG2E/(prf*prf);
  float emd = EXP2F(-LOG2E*d);
  for (int k = 0; k < NRAD; ++k){
    float mu = stf + (1.0f - stf)*((float)k*(1.0f/95.0f));
    float t = emd - mu;
    remb[(size_t)el*NRAD + k] = f2b(env * EXP2F(-betaL*t*t));
  }
}

// ---------------- node embedding + layernorm (+ fused accumulator zeroing) ----------------
__global__ __launch_bounds__(128) void k_embed(const int* __restrict__ z,
    const float* __restrict__ ne_w, const float* __restrict__ ne_b,
    float* __restrict__ s, float* __restrict__ h0,
    float* __restrict__ S, float* __restrict__ vecacc)
{
  int n = blockIdx.x; int h = threadIdx.x;
  float x = ne_w[(size_t)z[n]*HIDDIM + h] + ne_b[h];
  __shared__ float red[128];
  red[h] = x; __syncthreads();
  for (int o = 64; o > 0; o >>= 1){ if (h < o) red[h] += red[h+o]; __syncthreads(); }
  float mean = red[0] * (1.f/128.f);
  __syncthreads();
  float dx = x - mean;
  red[h] = dx*dx; __syncthreads();
  for (int o = 64; o > 0; o >>= 1){ if (h < o) red[h] += red[h+o]; __syncthreads(); }
  float var = red[0] * (1.f/128.f);
  float y = dx * rsqrtf(var + 1e-5f);
  s[(size_t)n*HIDDIM + h] = y;
  h0[(size_t)n*HIDDIM + h] = y;
  float* Sr = &S[(size_t)n*384 + h];
  float* Vr = &vecacc[(size_t)n*384 + h];
  Sr[0]=0.f; Sr[128]=0.f; Sr[256]=0.f;
  Vr[0]=0.f; Vr[128]=0.f; Vr[256]=0.f;
}

// LN -> xln_b, plus fused s -> sb conversion
__global__ __launch_bounds__(128) void k_ln(const float* __restrict__ src, ushortT* __restrict__ dst,
    const float* __restrict__ g, const float* __restrict__ b, ushortT* __restrict__ sb)
{
  int n = blockIdx.x; int h = threadIdx.x;
  float x = src[(size_t)n*HIDDIM + h];
  sb[(size_t)n*HIDDIM + h] = f2b(x);
  __shared__ float red[128];
  red[h] = x; __syncthreads();
  for (int o = 64; o > 0; o >>= 1){ if (h < o) red[h] += red[h+o]; __syncthreads(); }
  float mean = red[0] * (1.f/128.f);
  __syncthreads();
  float dx = x - mean;
  red[h] = dx*dx; __syncthreads();
  for (int o = 64; o > 0; o >>= 1){ if (h < o) red[h] += red[h+o]; __syncthreads(); }
  float var = red[0] * (1.f/128.f);
  float y = dx * rsqrtf(var + 1e-5f);
  dst[(size_t)n*HIDDIM + h] = f2b(y * g[h] + b[h]);
}

// ---------------- rowptr-based segment sums (one block per node) ----------------
__global__ __launch_bounds__(128) void k_seg1n(const int* __restrict__ rowptr,
    const int* __restrict__ jp, int o, int Cc,
    const float* __restrict__ h0, const ushortT* __restrict__ rhid,
    float* __restrict__ s)
{
  int i = blockIdx.x, h = threadIdx.x;
  int b = rowptr[i], e = rowptr[i+1];
  if (b < o) b = o;
  int hi = o + Cc; if (e > hi) e = hi;
  if (b >= e) return;
  float acc = 0.f;
  int m = b;
  for (; m + 1 < e; m += 2){
    int j0 = jp[m], j1 = jp[m+1];
    float r0 = b2f(rhid[(size_t)(m-o)*HIDDIM + h]);
    float r1 = b2f(rhid[(size_t)(m+1-o)*HIDDIM + h]);
    acc += h0[(size_t)j0*HIDDIM + h]*r0 + h0[(size_t)j1*HIDDIM + h]*r1;
  }
  if (m < e) acc += h0[(size_t)jp[m]*HIDDIM + h] * b2f(rhid[(size_t)(m-o)*HIDDIM + h]);
  s[(size_t)i*HIDDIM + h] += acc;
}

__global__ __launch_bounds__(128) void k_seg2n(const int* __restrict__ rowptr,
    const int* __restrict__ jp, int o, int Cc,
    const ushortT* __restrict__ slin, const ushortT* __restrict__ rhid,
    const float* __restrict__ edb, float* __restrict__ S)
{
  int i = blockIdx.x, h = threadIdx.x;
  int b = rowptr[i], e = rowptr[i+1];
  if (b < o) b = o;
  int hi = o + Cc; if (e > hi) e = hi;
  if (b >= e) return;
  float a0 = 0.f, a1 = 0.f, a2 = 0.f;
  int m = b;
  for (; m + 1 < e; m += 2){
    int ml = m - o, ml2 = ml + 1;
    float u0 = b2f(slin[(size_t)jp[m]*HIDDIM + h])   * b2f(rhid[(size_t)ml*HIDDIM + h]);
    float u1 = b2f(slin[(size_t)jp[m+1]*HIDDIM + h]) * b2f(rhid[(size_t)ml2*HIDDIM + h]);
    a0 += u0*edb[3*ml]   + u1*edb[3*ml2];
    a1 += u0*edb[3*ml+1] + u1*edb[3*ml2+1];
    a2 += u0*edb[3*ml+2] + u1*edb[3*ml2+2];
  }
  if (m < e){
    int ml = m - o;
    float u0 = b2f(slin[(size_t)jp[m]*HIDDIM + h]) * b2f(rhid[(size_t)ml*HIDDIM + h]);
    a0 += u0*edb[3*ml]; a1 += u0*edb[3*ml+1]; a2 += u0*edb[3*ml+2];
  }
  float* base = &S[(size_t)i*384 + h];
  base[0]   += a0;
  base[128] += a1;
  base[256] += a2;
}

__global__ __launch_bounds__(128) void k_seg3n(const int* __restrict__ rowptr,
    int o, int Cc,
    const ushortT* __restrict__ mb, const float* __restrict__ edb,
    float* __restrict__ s, float* __restrict__ vecacc)
{
  int i = blockIdx.x, h = threadIdx.x;
  int b = rowptr[i], e = rowptr[i+1];
  if (b < o) b = o;
  int hi = o + Cc; if (e > hi) e = hi;
  if (b >= e) return;
  const float is128 = 0.08838834764831845f;
  float am = 0.f, v0 = 0.f, v1 = 0.f, v2 = 0.f;
  int m = b;
  for (; m + 1 < e; m += 2){
    int ml = m - o, ml2 = ml + 1;
    float m1a = b2f(mb[(size_t)ml*384 + h]);
    float m1b = b2f(mb[(size_t)ml2*384 + h]);
    float mma = b2f(mb[(size_t)ml*384 + 256 + h]) * is128;
    float mmb = b2f(mb[(size_t)ml2*384 + 256 + h]) * is128;
    am += m1a + m1b;
    v0 += mma*edb[3*ml]   + mmb*edb[3*ml2];
    v1 += mma*edb[3*ml+1] + mmb*edb[3*ml2+1];
    v2 += mma*edb[3*ml+2] + mmb*edb[3*ml2+2];
  }
  if (m < e){
    int ml = m - o;
    float m1 = b2f(mb[(size_t)ml*384 + h]);
    float mm = b2f(mb[(size_t)ml*384 + 256 + h]) * is128;
    am += m1;
    v0 += mm*edb[3*ml]; v1 += mm*edb[3*ml+1]; v2 += mm*edb[3*ml+2];
  }
  s[(size_t)i*HIDDIM + h] += am;
  float* base = &vecacc[(size_t)i*384 + h];
  base[0]   += v0;
  base[128] += v1;
  base[256] += v2;
}

// ---------------- scalarize v5: 4 edges/block, two independent f2 chains ----------------
__global__ __launch_bounds__(256) void k_scal5(
  const int* __restrict__ jp, const int* __restrict__ ip, int off, int Cc,
  const float* __restrict__ S,
  const float* __restrict__ edb, const float* __restrict__ ecv,
  const float* __restrict__ rb,
  const float* __restrict__ l3s,
  ushortT* __restrict__ ews)
{
  int e0 = blockIdx.x*4;
  int e1 = (e0+1 < Cc) ? e0+1 : e0;
  int e2 = (e0+2 < Cc) ? e0+2 : e0;
  int e3 = (e0+3 < Cc) ? e0+3 : e0;
  int t = threadIdx.x;
  int which = t >> 7, h = t & 127;
  int nA0 = which ? jp[off+e0] : ip[off+e0];
  int nA1 = which ? jp[off+e1] : ip[off+e1];
  int nB0 = which ? jp[off+e2] : ip[off+e2];
  int nB1 = which ? jp[off+e3] : ip[off+e3];
  f2_t Af00 = {edb[3*e0],   edb[3*e1]};
  f2_t Af01 = {edb[3*e0+1], edb[3*e1+1]};
  f2_t Af02 = {edb[3*e0+2], edb[3*e1+2]};
  f2_t Af10 = {ecv[6*e0],   ecv[6*e1]};
  f2_t Af11 = {ecv[6*e0+1], ecv[6*e1+1]};
  f2_t Af12 = {ecv[6*e0+2], ecv[6*e1+2]};
  f2_t Af20 = {ecv[6*e0+3], ecv[6*e1+3]};
  f2_t Af21 = {ecv[6*e0+4], ecv[6*e1+4]};
  f2_t Af22 = {ecv[6*e0+5], ecv[6*e1+5]};
  f2_t Arb  = {rb[e0], rb[e1]};
  f2_t Bf00 = {edb[3*e2],   edb[3*e3]};
  f2_t Bf01 = {edb[3*e2+1], edb[3*e3+1]};
  f2_t Bf02 = {edb[3*e2+2], edb[3*e3+2]};
  f2_t Bf10 = {ecv[6*e2],   ecv[6*e3]};
  f2_t Bf11 = {ecv[6*e2+1], ecv[6*e3+1]};
  f2_t Bf12 = {ecv[6*e2+2], ecv[6*e3+2]};
  f2_t Bf20 = {ecv[6*e2+3], ecv[6*e3+3]};
  f2_t Bf21 = {ecv[6*e2+4], ecv[6*e3+4]};
  f2_t Bf22 = {ecv[6*e2+5], ecv[6*e3+5]};
  f2_t Brb  = {rb[e2], rb[e3]};
  const float* SA0 = &S[(size_t)nA0*384];
  const float* SA1 = &S[(size_t)nA1*384];
  const float* SB0 = &S[(size_t)nB0*384];
  const float* SB1 = &S[(size_t)nB1*384];
  f2_t AS0 = {SA0[h],     SA1[h]};
  f2_t AS1 = {SA0[128+h], SA1[128+h]};
  f2_t AS2 = {SA0[256+h], SA1[256+h]};
  f2_t BS0 = {SB0[h],     SB1[h]};
  f2_t BS1 = {SB0[128+h], SB1[128+h]};
  f2_t BS2 = {SB0[256+h], SB1[256+h]};
  f2_t Av0 = AS0*Af00 + AS1*Af01 + AS2*Af02;
  f2_t Av1t = AS0*Af10 + AS1*Af11 + AS2*Af12;
  f2_t Av1 = {fabsf(Av1t.x), fabsf(Av1t.y)};
  f2_t Av2 = AS0*Af20 + AS1*Af21 + AS2*Af22;
  f2_t Bv0 = BS0*Bf00 + BS1*Bf01 + BS2*Bf02;
  f2_t Bv1t = BS0*Bf10 + BS1*Bf11 + BS2*Bf12;
  f2_t Bv1 = {fabsf(Bv1t.x), fabsf(Bv1t.y)};
  f2_t Bv2 = BS0*Bf20 + BS1*Bf21 + BS2*Bf22;
  f2_t Aout = {0.f, 0.f}, Bout = {0.f, 0.f};
  #pragma unroll
  for (int u = 0; u < 32; ++u){
    float w0 = l3s[u], w1 = l3s[32+u], w2 = l3s[64+u];
    float bb = l3s[96+u], ww = l3s[128+u];
    f2_t At = Av0*w0 + Av1*w1 + Av2*w2 + bb;
    f2_t Bt = Bv0*w0 + Bv1*w1 + Bv2*w2 + bb;
    f2_t Ar, Br;
    Ar.x = RCPF(1.f + EXP2F(At.x));
    Ar.y = RCPF(1.f + EXP2F(At.y));
    Br.x = RCPF(1.f + EXP2F(Bt.x));
    Br.y = RCPF(1.f + EXP2F(Bt.y));
    Aout += (At*Ar)*ww;
    Bout += (Bt*Br)*ww;
  }
  float sb2 = l3s[160];
  f2_t Ares = (Aout + sb2 + Av0) * Arb;
  f2_t Bres = (Bout + sb2 + Bv0) * Brb;
  size_t base = (size_t)which*128 + h;
  ews[(size_t)e0*256 + base] = f2b(Ares.x);
  if (e0+1 < Cc) ews[(size_t)e1*256 + base] = f2b(Ares.y);
  if (e0+2 < Cc) ews[(size_t)e2*256 + base] = f2b(Bres.x);
  if (e0+3 < Cc) ews[(size_t)e3*256 + base] = f2b(Bres.y);
}

// ---------------- bf16 MFMA GEMM ----------------
// A: MxK bf16 row-major; BT: NxK bf16 row-major. N%128==0, K%32==0.
// epi: 0 none, 1 silu, 2 *rowscale[row], 3 *mul1b[row,col]*xhpb[jidx[row],col]
// skipTile >= 0: that 128-col tile not computed (grid.x one smaller).
// A1 != nullptr: split-A — K [0,256) from A (stride 256), [256,384) from A1
// (stride 128), [384,480) from A2 (stride 96).
__global__ __launch_bounds__(256) void mgemm(
  const ushortT* __restrict__ A, const ushortT* __restrict__ BT,
  const float* __restrict__ bias,
  float* __restrict__ Cf, ushortT* __restrict__ Cb,
  int M, int N, int K, int epi,
  const float* __restrict__ rowscale,
  const ushortT* __restrict__ mul1b,
  const ushortT* __restrict__ xhpb,
  const int* __restrict__ jidx,
  int skipTile,
  const ushortT* __restrict__ A1, const ushortT* __restrict__ A2)
{
  const int tid = threadIdx.x;
  const int w = tid >> 6;
  const int lane = tid & 63;
  const int l15 = lane & 15;
  const int q = lane >> 4;
  const int wm = w & 1, wn = w >> 1;
  const int rowBase = blockIdx.y * 128;
  int bx = blockIdx.x;
  if (skipTile >= 0 && bx >= skipTile) bx++;
  const int colBase = bx * 128;
  f4_t acc[4][4] = {};

#ifdef HAVE_GLDS
  __shared__ ushortT As[128*32];
  __shared__ ushortT Bs[128*32];
  const int rS = 32*w + (lane >> 2);
  const int kS = (lane & 3) << 3;
  ushortT* lA0 = &As[(32*w)*32];
  ushortT* lA1 = &As[(32*w+16)*32];
  ushortT* lB0 = &Bs[(32*w)*32];
  ushortT* lB1 = &Bs[(32*w+16)*32];
  int ra0 = rowBase + rS;      if (ra0 >= M) ra0 = M-1;
  int ra1 = rowBase + rS + 16; if (ra1 >= M) ra1 = M-1;
  const ushortT* gB0 = BT + (size_t)(colBase + rS)*K + kS;
  const ushortT* gB1 = BT + (size_t)(colBase + rS + 16)*K + kS;
  for (int k0 = 0; k0 < K; k0 += 32){
    const ushortT* srcA; size_t strA; int kc;
    if (!A1){ srcA = A; strA = (size_t)K; kc = k0; }
    else if (k0 < 256){ srcA = A; strA = 256; kc = k0; }
    else if (k0 < 384){ srcA = A1; strA = 128; kc = k0 - 256; }
    else { srcA = A2; strA = 96; kc = k0 - 384; }
    glds16(srcA + (size_t)ra0*strA + kc + kS, lA0);
    glds16(srcA + (size_t)ra1*strA + kc + kS, lA1);
    glds16(gB0 + k0, lB0);
    glds16(gB1 + k0, lB1);
    __syncthreads();
    bf8_t a[4], b[4];
    #pragma unroll
    for (int mt = 0; mt < 4; ++mt)
      a[mt] = *(const bf8_t*)&As[(wm*64 + mt*16 + l15)*32 + q*8];
    #pragma unroll
    for (int nt = 0; nt < 4; ++nt)
      b[nt] = *(const bf8_t*)&Bs[(wn*64 + nt*16 + l15)*32 + q*8];
    #pragma unroll
    for (int mt = 0; mt < 4; ++mt){
      #pragma unroll
      for (int nt = 0; nt < 4; ++nt)
        acc[mt][nt] = __builtin_amdgcn_mfma_f32_16x16x32_bf16(a[mt], b[nt], acc[mt][nt], 0, 0, 0);
    }
    __syncthreads();
  }
#else
  __shared__ ushortT As[128*48];
  __shared__ ushortT Bs[128*48];
  const int r0 = tid >> 2,         s0 = (tid & 3) << 3;
  const int r1 = (tid + 256) >> 2, s1 = ((tid + 256) & 3) << 3;
  for (int k0 = 0; k0 < K; k0 += 32){
    const ushortT* srcA; size_t strA; int kc;
    if (!A1){ srcA = A; strA = (size_t)K; kc = k0; }
    else if (k0 < 256){ srcA = A; strA = 256; kc = k0; }
    else if (k0 < 384){ srcA = A1; strA = 128; kc = k0 - 256; }
    else { srcA = A2; strA = 96; kc = k0 - 384; }
    int4 a0v = make_int4(0,0,0,0), a1v = make_int4(0,0,0,0);
    if (rowBase + r0 < M) a0v = *(const int4*)&srcA[(size_t)(rowBase + r0)*strA + kc + s0];
    if (rowBase + r1 < M) a1v = *(const int4*)&srcA[(size_t)(rowBase + r1)*strA + kc + s1];
    int4 b0v = *(const int4*)&BT[(size_t)(colBase + r0)*K + k0 + s0];
    int4 b1v = *(const int4*)&BT[(size_t)(colBase + r1)*K + k0 + s1];
    __syncthreads();
    *(int4*)&As[r0*48 + s0] = a0v;
    *(int4*)&As[r1*48 + s1] = a1v;
    *(int4*)&Bs[r0*48 + s0] = b0v;
    *(int4*)&Bs[r1*48 + s1] = b1v;
    __syncthreads();
    bf8_t a[4], b[4];
    #pragma unroll
    for (int mt = 0; mt < 4; ++mt)
      a[mt] = *(const bf8_t*)&As[(wm*64 + mt*16 + l15)*48 + q*8];
    #pragma unroll
    for (int nt = 0; nt < 4; ++nt)
      b[nt] = *(const bf8_t*)&Bs[(wn*64 + nt*16 + l15)*48 + q*8];
    #pragma unroll
    for (int mt = 0; mt < 4; ++mt){
      #pragma unroll
      for (int nt = 0; nt < 4; ++nt)
        acc[mt][nt] = __builtin_amdgcn_mfma_f32_16x16x32_bf16(a[mt], b[nt], acc[mt][nt], 0, 0, 0);
    }
  }
#endif

  #pragma unroll
  for (int mt = 0; mt < 4; ++mt){
    int row = rowBase + wm*64 + mt*16 + q*4;
    #pragma unroll
    for (int nt = 0; nt < 4; ++nt){
      int col = colBase + wn*64 + nt*16 + l15;
      float bv = bias ? bias[col] : 0.f;
      #pragma unroll
      for (int r = 0; r < 4; ++r){
        int rr = row + r;
        if (rr >= M) continue;
        float x = acc[mt][nt][r] + bv;
        if (epi == 1) x = silu_f(x);
        else if (epi == 2) x *= rowscale[rr];
        else if (epi == 3) x = x * b2f(mul1b[(size_t)rr*N + col]) * b2f(xhpb[(size_t)jidx[rr]*N + col]);
        if (Cb) Cb[(size_t)rr*N + col] = f2b(x);
        else    Cf[(size_t)rr*N + col] = x;
      }
    }
  }
}

// ---------------- fte prep ----------------
__global__ __launch_bounds__(128) void k_fte_pre(const float* __restrict__ vpc,
    const float* __restrict__ s, ushortT* __restrict__ catb, float* __restrict__ vdot,
    int no)
{
  int nl = blockIdx.x, h = threadIdx.x;
  int n = no + nl;
  const float* base = &vpc[(size_t)nl*768];
  float a0 = base[h],       a1 = base[256+h],     a2 = base[512+h];
  float c0 = base[128+h],   c1 = base[384+h],     c2 = base[640+h];
  float scal = sqrtf(a0*a0 + a1*a1 + a2*a2 + 1e-10f);
  float vd = (a0*c0 + a1*c1 + a2*c2) * 0.08838834764831845f;
  catb[(size_t)n*256 + h] = f2b(s[(size_t)n*HIDDIM + h]);
  catb[(size_t)n*256 + 128 + h] = f2b(scal);
  vdot[(size_t)n*HIDDIM + h] = vd;
}

// ---------------- final ----------------
__global__ __launch_bounds__(128) void k_out(const float* __restrict__ xh2,
    const float* __restrict__ vdot, const float* __restrict__ s,
    const float* __restrict__ ow, const float* __restrict__ ob,
    float* __restrict__ nodeout)
{
  int n = blockIdx.x, h = threadIdx.x;
  float a1 = xh2[(size_t)n*384 + h];
  float a2 = xh2[(size_t)n*384 + 128 + h];
  float sv = s[(size_t)n*HIDDIM + h] + (a1 + a2*vdot[(size_t)n*HIDDIM + h]) * 0.7071067811865476f;
  __shared__ float red[128];
  red[h] = sv * ow[h];
  __syncthreads();
  for (int o = 64; o > 0; o >>= 1){ if (h < o) red[h] += red[h+o]; __syncthreads(); }
  if (h == 0) nodeout[n] = red[0] + ob[0];
}

__global__ __launch_bounds__(256) void k_final(const float* __restrict__ nodeout,
    const int* __restrict__ batch, void* __restrict__ out, int Nn, const int* flags)
{
  int g = blockIdx.x;
  __shared__ float rs[256], rc[256];
  float sm = 0.f, c = 0.f;
  for (int n = threadIdx.x; n < Nn; n += 256){
    if (batch[n] == g){ sm += nodeout[n]; c += 1.f; }
  }
  rs[threadIdx.x] = sm; rc[threadIdx.x] = c;
  __syncthreads();
  for (int o = 128; o > 0; o >>= 1){
    if (threadIdx.x < o){ rs[threadIdx.x] += rs[threadIdx.x+o]; rc[threadIdx.x] += rc[threadIdx.x+o]; }
    __syncthreads();
  }
  if (threadIdx.x == 0){
    float v = (rc[0] > 0.f) ? rs[0]/rc[0] : 0.f;
    if (flags[2] == 0) ((__hip_bfloat16*)out)[g] = __float2bfloat16(v);
    else ((float*)out)[g] = v;
  }
}

// =====================================================================
extern "C" void kernel_launch(void* const* d_in, const int* in_sizes, int n_in,
                              void* d_out, int out_size, void* d_ws, size_t ws_size,
                              hipStream_t stream)
{
  const int N = in_sizes[0] / 3;
  const int E = in_sizes[3] / 2;

  size_t off = 0;
  auto alloc = [&](size_t n)->float*{
    float* p = (float*)d_ws + off;
    off += (n + 3) & ~(size_t)3;
    return p;
  };
  auto allocU = [&](size_t n)->ushortT*{ return (ushortT*)alloc((n + 1) / 2); };

  int* flags  = (int*)alloc(4);
  int* deg    = (int*)alloc((size_t)N);
  int* cursor = (int*)alloc((size_t)N);
  size_t zeroHdr = off;
  int* zi     = (int*)alloc((size_t)N);
  int* bi     = (int*)alloc((size_t)N);
  int* eii    = (int*)alloc((size_t)2*E);
  int* rowptr = (int*)alloc((size_t)N + 4);
  int* jp     = (int*)alloc((size_t)E);
  int* ipp    = (int*)alloc((size_t)E);
  float* l3s  = alloc(164);

  float* pos = alloc((size_t)N*3);
  float* w[31];
  for (int t = 0; t < 31; ++t) w[t] = alloc((size_t)in_sizes[4+t]);
  float* rl_b1=w[1];  float* rl_b2=w[3];
  float* ne_w =w[4];  float* ne_b =w[5];  float* sv_b =w[7];
  float* l3_w1=w[8];  float* l3_b1=w[9];  float* l3_w2=w[10]; float* l3_b2=w[11];
  float* mp_w =w[12]; float* mp_b =w[13]; float* xp_b1=w[15];
  float* xp_b2=w[17]; float* rp_b =w[19];
  float* ip_b1=w[21]; float* ip_b2=w[23];
  float* fte_b1=w[26];float* fte_b2=w[28];float* out_w=w[29]; float* out_b=w[30];

  ushortT* wt_rl1 = allocU(96*128);
  ushortT* wt_rl2 = allocU(128*128);
  ushortT* wt_sv  = allocU(128*128);
  ushortT* wt_xp1 = allocU(128*128);
  ushortT* wt_xp2 = allocU((size_t)128*384);
  ushortT* wt_rp  = allocU((size_t)96*384);
  ushortT* wt_ip1 = allocU((size_t)480*384);
  ushortT* wt_ip2 = allocU((size_t)384*384);
  ushortT* wt_feq = allocU((size_t)128*256);
  ushortT* wt_ft1 = allocU((size_t)256*128);
  ushortT* wt_ft2 = allocU((size_t)128*384);

  float* s    = alloc((size_t)N*HIDDIM);
  float* h0   = alloc((size_t)N*HIDDIM);      // -> vdot overlay after seg1
  ushortT* sb     = allocU((size_t)N*HIDDIM); // sb+slin_b contiguous -> catb overlay
  ushortT* slin_b = allocU((size_t)N*HIDDIM);
  ushortT* xln_b  = allocU((size_t)N*HIDDIM);
  ushortT* hb     = allocU((size_t)N*HIDDIM);
  float* S    = alloc((size_t)N*384);         // -> vab overlay in phase F
  float* vecacc = alloc((size_t)N*384);       // -> xh2 overlay after f2b
  ushortT* xh_b = allocU((size_t)N*384);
  float* nodeout = alloc((size_t)N);
  float* vdot = h0;
  ushortT* catb = sb;
  ushortT* vab = (ushortT*)S;
  float* xh2 = vecacc;

  size_t wsF = ws_size / sizeof(float);

  // tier selection:
  //  tier2: persist edb(3)+ecv(6)+rb(1)+remb(48)+rhid(64) = 122 f/edge; chunk 576 f/edge
  //  tier1: persist edb+rhid (67 f/edge);                  chunk 631 f/edge
  //  tier0: nothing persists;                              chunk 698 f/edge
  int tier = 0; size_t p = 698;
  if (off + 122ULL*(size_t)E + 16 + 256ULL*576 <= wsF){ tier = 2; p = 576; }
  else if (off + 67ULL*(size_t)E + 16 + 256ULL*631 <= wsF){ tier = 1; p = 631; }

  ushortT *rhid_a = nullptr, *remb_a = nullptr;
  float *edb_a = nullptr, *ecv_a = nullptr, *rb_a = nullptr;
  if (tier >= 1){
    rhid_a = allocU((size_t)E*128);
    edb_a  = alloc((size_t)3*E);
  }
  if (tier == 2){
    ecv_a  = alloc((size_t)6*E);
    rb_a   = alloc((size_t)E);
    remb_a = allocU((size_t)E*96);
  }
  size_t availF = (wsF > off) ? (wsF - off) : 0;
  if (availF < 256*p){
    k_sentinel<<<1, 64, 0, stream>>>((__hip_bfloat16*)d_out, out_size,
                                     (float)(double)(ws_size >> 20));
    return;
  }
  size_t Cs = availF / p; if (Cs > (size_t)E) Cs = E;
  int C = (int)(Cs & ~(size_t)15);
  if (C < 256) C = 256;

  float* scratch0 = (float*)d_ws + off;
  ushortT* remb_l = nullptr; float *ecv_l = nullptr, *rb_l = nullptr;
  if (tier <= 1){
    remb_l = allocU((size_t)C*96);   // 48C
    ecv_l  = alloc((size_t)6*C);
    rb_l   = alloc((size_t)C);
  }
  float* edb_l = nullptr; ushortT* rhid_l = nullptr;
  if (tier == 0){
    edb_l  = alloc((size_t)3*C);
    rhid_l = allocU((size_t)C*128);
  }
  ushortT* ewReg = allocU((size_t)C*384);     // 192C: ews (256/edge) then Rmb (384/edge)
  ushortT* R2b  = allocU((size_t)C*384);      // 192C ; R2rl overlays
  ushortT* R1b  = allocU((size_t)C*384);      // 192C
  ushortT* ews  = ewReg;
  ushortT* Rmb  = ewReg;
  ushortT* R2rl = R2b;
  float* vpc = scratch0;
  size_t scratchF = (size_t)C*p;

  auto mg = [&](const ushortT* A, const ushortT* BT, const float* bias,
                float* Cf, ushortT* Cb, int M, int Nc, int K, int epi,
                const float* rowscale = nullptr, const ushortT* mul1b = nullptr,
                const ushortT* xhpb = nullptr, const int* jidx = nullptr,
                int skipTile = -1,
                const ushortT* A1 = nullptr, const ushortT* A2 = nullptr){
    dim3 grid(Nc/128 - (skipTile >= 0 ? 1 : 0), (M + 127)/128);
    mgemm<<<grid, 256, 0, stream>>>(A, BT, bias, Cf, Cb, M, Nc, K, epi,
                                    rowscale, mul1b, xhpb, jidx, skipTile, A1, A2);
  };

  // 0) zero header, detect dtypes, int-normalize (+deg histogram)
  k_zero<<<64, 256, 0, stream>>>((float*)flags, (int)zeroHdr);
  k_detect<<<64, 256, 0, stream>>>((const ushortT*)d_in[0], in_sizes[0],
                                   (const int*)d_in[2], in_sizes[2], flags);
  k_iconv<<<1024, 256, 0, stream>>>((const int*)d_in[1], (const int*)d_in[2],
                                    (const int*)d_in[3], zi, bi, eii, N, E, flags, deg);

  // 1) float conversions + transposed bf16 weights + l3 prescale
  ConvArgs ca;
  ca.d[0] = { (const ushortT*)d_in[0], pos, in_sizes[0] };
  for (int t = 0; t < 31; ++t)
    ca.d[1+t] = { (const ushortT*)d_in[4+t], w[t], in_sizes[4+t] };
  k_conv<<<dim3(32, 32), 256, 0, stream>>>(ca, 32, flags);
  k_l3pre<<<1, 192, 0, stream>>>(l3_w1, l3_b1, l3_w2, l3_b2, l3s);

  TArgs ta;
  ta.d[0]  = { (const ushortT*)d_in[4],  wt_rl1, 96, 128 };
  ta.d[1]  = { (const ushortT*)d_in[6],  wt_rl2, 128, 128 };
  ta.d[2]  = { (const ushortT*)d_in[10], wt_sv,  128, 128 };
  ta.d[3]  = { (const ushortT*)d_in[18], wt_xp1, 128, 128 };
  ta.d[4]  = { (const ushortT*)d_in[20], wt_xp2, 128, 384 };
  ta.d[5]  = { (const ushortT*)d_in[22], wt_rp,  96, 384 };
  ta.d[6]  = { (const ushortT*)d_in[24], wt_ip1, 480, 384 };
  ta.d[7]  = { (const ushortT*)d_in[26], wt_ip2, 384, 384 };
  ta.d[8]  = { (const ushortT*)d_in[28], wt_feq, 128, 256 };
  ta.d[9]  = { (const ushortT*)d_in[29], wt_ft1, 256, 128 };
  ta.d[10] = { (const ushortT*)d_in[31], wt_ft2, 128, 384 };
  k_wt<<<dim3(48, 11), 256, 0, stream>>>(ta, 11, flags);

  // 2) CSR scan + scatter
  k_csr_scan<<<1, 256, 0, stream>>>(deg, rowptr, N);
  k_csr_scatter<<<(E + 255)/256, 256, 0, stream>>>(eii, E, rowptr, cursor, jp, ipp);

  // 3) node embedding (+ S/vecacc zero fused)
  k_embed<<<N, 128, 0, stream>>>(zi, ne_w, ne_b, s, h0, S, vecacc);

  // pre-pass + Phase B
  if (tier == 2){
    k_geom<<<(E + 255)/256, 256, 0, stream>>>(pos, jp, ipp, 0, E,
                                              edb_a, ecv_a, rb_a, remb_a);
    // rl MLP with big chunks: full 576C scratch free as R2 temp (64 f/edge)
    {
      size_t CrlS = ((size_t)C*576)/64; if (CrlS > (size_t)E) CrlS = E;
      int Crl = (int)(CrlS & ~(size_t)15); if (Crl < 256) Crl = 256;
      ushortT* R2big = (ushortT*)scratch0;
      for (int o = 0; o < E; o += Crl){
        int Cc = (E - o < Crl) ? (E - o) : Crl;
        mg(remb_a + (size_t)o*96, wt_rl1, rl_b1, nullptr, R2big, Cc, 128, 96, 1);
        mg(R2big, wt_rl2, rl_b2, nullptr, rhid_a + (size_t)o*128, Cc, 128, 128, 2, rb_a + o);
      }
    }
    k_seg1n<<<N, 128, 0, stream>>>(rowptr, jp, 0, E, h0, rhid_a, s);
  } else if (tier == 1){
    for (int o = 0; o < E; o += C){
      int Cc = (E - o < C) ? (E - o) : C;
      k_geom<<<(Cc + 255)/256, 256, 0, stream>>>(pos, jp, ipp, o, Cc,
                                                 edb_a + (size_t)3*o, nullptr, rb_l, remb_l);
      mg(remb_l, wt_rl1, rl_b1, nullptr, R2rl, Cc, 128, 96, 1);
      mg(R2rl, wt_rl2, rl_b2, nullptr, rhid_a + (size_t)o*128, Cc, 128, 128, 2, rb_l);
    }
    k_seg1n<<<N, 128, 0, stream>>>(rowptr, jp, 0, E, h0, rhid_a, s);
  } else {
    for (int o = 0; o < E; o += C){
      int Cc = (E - o < C) ? (E - o) : C;
      k_geom<<<(Cc + 255)/256, 256, 0, stream>>>(pos, jp, ipp, o, Cc,
                                                 edb_l, nullptr, rb_l, remb_l);
      mg(remb_l, wt_rl1, rl_b1, nullptr, R2rl, Cc, 128, 96, 1);
      mg(R2rl, wt_rl2, rl_b2, nullptr, rhid_l, Cc, 128, 128, 2, rb_l);
      k_seg1n<<<N, 128, 0, stream>>>(rowptr, jp, o, Cc, h0, rhid_l, s);
    }
  }

  // Phase C: slin, xln(+sb), xh (xh cols 128-255 dead -> skip tile 1)
  k_ln<<<N, 128, 0, stream>>>(s, xln_b, mp_w, mp_b, sb);
  mg(sb, wt_sv, sv_b, nullptr, slin_b, N, 128, 128, 1);
  mg(xln_b, wt_xp1, xp_b1, nullptr, hb, N, 128, 128, 1);
  mg(hb, wt_xp2, xp_b2, nullptr, xh_b, N, 384, 128, 0, nullptr, nullptr, nullptr, nullptr, 1);

  // Phase D: seg2
  if (tier >= 1){
    k_seg2n<<<N, 128, 0, stream>>>(rowptr, jp, 0, E, slin_b, rhid_a, edb_a, S);
  } else {
    for (int o = 0; o < E; o += C){
      int Cc = (E - o < C) ? (E - o) : C;
      k_geom<<<(Cc + 255)/256, 256, 0, stream>>>(pos, jp, ipp, o, Cc,
                                                 edb_l, nullptr, rb_l, remb_l);
      mg(remb_l, wt_rl1, rl_b1, nullptr, R2rl, Cc, 128, 96, 1);
      mg(R2rl, wt_rl2, rl_b2, nullptr, rhid_l, Cc, 128, 128, 2, rb_l);
      k_seg2n<<<N, 128, 0, stream>>>(rowptr, jp, o, Cc, slin_b, rhid_l, edb_l, S);
    }
  }

  // Phase E: per-edge big MLPs + seg3 (rp/ip2 skip dead middle tile; ip1 split-A)
  for (int o = 0; o < E; o += C){
    int Cc = (E - o < C) ? (E - o) : C;
    const ushortT *rhid_p, *remb_p;
    const float *edb_p, *ecv_p, *rb_p;
    if (tier == 2){
      rhid_p = rhid_a + (size_t)o*128;
      edb_p  = edb_a + (size_t)3*o;
      ecv_p  = ecv_a + (size_t)6*o;
      rb_p   = rb_a + o;
      remb_p = remb_a + (size_t)o*96;
    } else if (tier == 1){
      k_geom<<<(Cc + 255)/256, 256, 0, stream>>>(pos, jp, ipp, o, Cc,
                                                 edb_a + (size_t)3*o, ecv_l, rb_l, remb_l);
      rhid_p = rhid_a + (size_t)o*128;
      edb_p  = edb_a + (size_t)3*o;
      ecv_p  = ecv_l; rb_p = rb_l; remb_p = remb_l;
    } else {
      k_geom<<<(Cc + 255)/256, 256, 0, stream>>>(pos, jp, ipp, o, Cc,
                                                 edb_l, ecv_l, rb_l, remb_l);
      mg(remb_l, wt_rl1, rl_b1, nullptr, R2rl, Cc, 128, 96, 1);
      mg(R2rl, wt_rl2, rl_b2, nullptr, rhid_l, Cc, 128, 128, 2, rb_l);
      rhid_p = rhid_l; edb_p = edb_l; ecv_p = ecv_l; rb_p = rb_l; remb_p = remb_l;
    }
    k_scal5<<<(Cc + 3)/4, 256, 0, stream>>>(jp, ipp, o, Cc, S,
                                            edb_p, ecv_p, rb_p, l3s, ews);
    mg(remb_p, wt_rp, rp_b, nullptr, R1b, Cc, 384, 96, 0,
       nullptr, nullptr, nullptr, nullptr, 1);
    mg(ews, wt_ip1, ip_b1, nullptr, R2b, Cc, 384, 480, 1,
       nullptr, nullptr, nullptr, nullptr, -1, rhid_p, remb_p);
    mg(R2b, wt_ip2, ip_b2, nullptr, Rmb, Cc, 384, 384, 3,
       nullptr, R1b, xh_b, jp + o, 1);
    k_seg3n<<<N, 128, 0, stream>>>(rowptr, o, Cc, Rmb, edb_p, s, vecacc);
  }

  // Phase F: fte
  k_f2b<<<1024, 256, 0, stream>>>(vecacc, vab, N*384);
  int Cn = (int)(scratchF / 768);
  if (Cn > N) Cn = N;
  for (int no = 0; no < N; no += Cn){
    int Cc = (N - no < Cn) ? (N - no) : Cn;
    mg(vab + (size_t)no*384, wt_feq, nullptr, vpc, nullptr, 3*Cc, 256, 128, 0);
    k_fte_pre<<<Cc, 128, 0, stream>>>(vpc, s, catb, vdot, no);
  }
  mg(catb, wt_ft1, fte_b1, nullptr, hb, N, 128, 256, 1);
  mg(hb, wt_ft2, fte_b2, xh2, nullptr, N, 384, 128, 0);

  // Phase G
  k_out<<<N, 128, 0, stream>>>(xh2, vdot, s, out_w, out_b, nodeout);
  k_final<<<out_size, 256, 0, stream>>>(nodeout, bi, d_out, N, flags);
}

// Round 13
// 1817.819 us; speedup vs baseline: 1.8104x; 1.8104x over previous
//
#include <hip/hip_runtime.h>
#include <hip/hip_bf16.h>
#include <math.h>

#define NRAD 96
#define HIDDIM 128
typedef unsigned short ushortT;

typedef __attribute__((ext_vector_type(8))) short bf8_t;   // 8 bf16 (4 VGPRs)
typedef __attribute__((ext_vector_type(4))) float f4_t;    // 4 fp32 acc
typedef __attribute__((ext_vector_type(2))) float f2_t;    // packed fp32 pair

#if defined(__has_builtin)
#  if __has_builtin(__builtin_amdgcn_global_load_lds)
#    define HAVE_GLDS 1
#  endif
#  if __has_builtin(__builtin_amdgcn_rcpf)
#    define RCPF(x) __builtin_amdgcn_rcpf(x)
#  endif
#  if __has_builtin(__builtin_amdgcn_exp2f)
#    define EXP2F(x) __builtin_amdgcn_exp2f(x)
#  endif
#  if __has_builtin(__builtin_amdgcn_cosf)
#    define COSR(x) __builtin_amdgcn_cosf(x)   /* cos(2*pi*x) */
#  endif
#endif
#ifndef RCPF
#  define RCPF(x) (1.f/(x))
#endif
#ifndef EXP2F
#  define EXP2F(x) exp2f(x)
#endif
#ifndef COSR
#  define COSR(x) cosf(6.2831853071795864f*(x))
#endif
#define LOG2E 1.44269504088896f
#define LN2   0.69314718055995f

__device__ __forceinline__ float silu_f(float x){
  return x * RCPF(1.f + EXP2F(-LOG2E*x));
}
__device__ __forceinline__ float b2f(ushortT u){ return __uint_as_float(((unsigned int)u) << 16); }
__device__ __forceinline__ ushortT f2b(float x){
  unsigned int u = __float_as_uint(x);
  unsigned int r = (u + 0x7fffu + ((u >> 16) & 1u)) >> 16;
  return (ushortT)r;
}

#ifdef HAVE_GLDS
__device__ __forceinline__ void glds16(const ushortT* g, ushortT* l){
  __builtin_amdgcn_global_load_lds(
      (const __attribute__((address_space(1))) ushortT*)g,
      (__attribute__((address_space(3))) ushortT*)l, 16, 0, 0);
}
#endif

// ---------------- dtype detection (parallel) ----------------
__global__ void k_detect(const ushortT* posw, int npos,
                         const int* batchw, int nb, int* flags){
  int tot = (npos < 4096 ? npos : 4096);
  int big = tot > nb ? tot : nb;
  int bad = 0, orv = 0;
  for (int t = blockIdx.x*blockDim.x + threadIdx.x; t < big; t += gridDim.x*blockDim.x){
    if (t < tot){
      float x = b2f(posw[t]);
      if (!(fabsf(x) <= 1000.f)) bad = 1;
    }
    if (t < nb && (t & 1)) orv |= batchw[t];
  }
  if (bad) atomicOr(&flags[2], 1);
  if (orv) atomicOr(&flags[3], 1);
}

__global__ void k_iconv(const int* zsrc, const int* bsrc, const int* esrc,
                        int* zi, int* bi, int* eii, int Nn, int E, const int* flags,
                        int* deg){
  int f = (flags[3] == 0) ? 1 : 0;   // 1 => int64
  int total = 2*Nn + 2*E;
  for (int t = blockIdx.x*blockDim.x + threadIdx.x; t < total; t += gridDim.x*blockDim.x){
    if (t < Nn) zi[t] = zsrc[(size_t)t << f];
    else if (t < 2*Nn) bi[t-Nn] = bsrc[(size_t)(t-Nn) << f];
    else {
      int e = t - 2*Nn;
      int v = esrc[(size_t)e << f];
      eii[e] = v;
      if (e >= E) atomicAdd(&deg[v], 1);
    }
  }
}

// ---------------- conversion: (bf16|f32) -> f32 ----------------
struct ConvDesc { const ushortT* src; float* dst; int n; };
struct ConvArgs { ConvDesc d[32]; };

__global__ void k_conv(ConvArgs a, int cnt, const int* flags){
  int y = blockIdx.y;
  if (y >= cnt) return;
  int f = (flags[2] == 0) ? 1 : 0;    // 1 => bf16
  const ushortT* s = a.d[y].src;
  float* dst = a.d[y].dst;
  int n = a.d[y].n;
  if (f){
    for (int t = blockIdx.x*blockDim.x + threadIdx.x; t < n; t += gridDim.x*blockDim.x)
      dst[t] = b2f(s[t]);
  } else {
    const float* sf = (const float*)s;
    for (int t = blockIdx.x*blockDim.x + threadIdx.x; t < n; t += gridDim.x*blockDim.x)
      dst[t] = sf[t];
  }
}

// prescale l3 weights: [0,96) w1*-log2e, [96,128) b1*-log2e, [128,160) w2*-ln2, [160] b2
__global__ void k_l3pre(const float* __restrict__ w1, const float* __restrict__ b1,
                        const float* __restrict__ w2, const float* __restrict__ b2,
                        float* __restrict__ l3s){
  int t = threadIdx.x;
  if (t < 96) l3s[t] = w1[t] * (-LOG2E);
  else if (t < 128) l3s[t] = b1[t-96] * (-LOG2E);
  else if (t < 160) l3s[t] = w2[t-128] * (-LN2);
  else if (t == 160) l3s[160] = b2[0];
}

// ---------------- weight transpose -> bf16 [N][K] ----------------
struct TDesc { const ushortT* src; ushortT* dst; int K, N; };
struct TArgs { TDesc d[12]; };

__global__ void k_wt(TArgs a, int cnt, const int* flags){
  int y = blockIdx.y;
  if (y >= cnt) return;
  int f = (flags[2] == 0) ? 1 : 0;
  const ushortT* s = a.d[y].src;
  ushortT* dst = a.d[y].dst;
  int K = a.d[y].K, N = a.d[y].N, tot = K*N;
  for (int t = blockIdx.x*blockDim.x + threadIdx.x; t < tot; t += gridDim.x*blockDim.x){
    int k = t / N, n = t - k*N;
    ushortT v = f ? s[t] : f2b(((const float*)s)[t]);
    dst[(size_t)n*K + k] = v;
  }
}

__global__ void k_f2b(const float* __restrict__ src, ushortT* __restrict__ dst, int n){
  for (int t = blockIdx.x*blockDim.x + threadIdx.x; t < n; t += gridDim.x*blockDim.x)
    dst[t] = f2b(src[t]);
}

__global__ void k_zero(float* __restrict__ p, int n){
  int t = blockIdx.x*blockDim.x + threadIdx.x;
  int stride = gridDim.x*blockDim.x;
  for (; t < n; t += stride) p[t] = 0.f;
}

__global__ void k_sentinel(__hip_bfloat16* out, int n, float val){
  int t = threadIdx.x;
  if (t < n) out[t] = __float2bfloat16(val);
}

// ---------------- CSR scan + scatter ----------------
__global__ void k_csr_scan(const int* __restrict__ deg, int* __restrict__ rowptr, int Nn){
  __shared__ int sh[256];
  __shared__ int carry;
  if (threadIdx.x == 0){ carry = 0; rowptr[0] = 0; }
  __syncthreads();
  for (int t0 = 0; t0 < Nn; t0 += 256){
    int idx = t0 + threadIdx.x;
    int v = (idx < Nn) ? deg[idx] : 0;
    sh[threadIdx.x] = v; __syncthreads();
    for (int o = 1; o < 256; o <<= 1){
      int u = (threadIdx.x >= o) ? sh[threadIdx.x - o] : 0;
      __syncthreads();
      sh[threadIdx.x] += u; __syncthreads();
    }
    if (idx < Nn) rowptr[idx + 1] = carry + sh[threadIdx.x];
    __syncthreads();
    if (threadIdx.x == 0) carry += sh[255];
    __syncthreads();
  }
}

__global__ void k_csr_scatter(const int* __restrict__ eii, int E,
                              const int* __restrict__ rowptr, int* __restrict__ cursor,
                              int* __restrict__ jp, int* __restrict__ ip){
  int e = blockIdx.x*blockDim.x + threadIdx.x;
  if (e >= E) return;
  int i = eii[E+e];
  int p = atomicAdd(&cursor[i], 1);
  int k = rowptr[i] + p;
  jp[k] = eii[e];
  ip[k] = i;
}

// ---------------- geometry + RBF ----------------
__global__ void k_geom(const float* __restrict__ pos,
                       const int* __restrict__ jp, const int* __restrict__ ip,
                       int off, int Cc,
                       float* __restrict__ edb, float* __restrict__ ecv,
                       float* __restrict__ rb, ushortT* __restrict__ remb)
{
  int el = blockIdx.x*blockDim.x + threadIdx.x;
  if (el >= Cc) return;
  int g = off + el;
  int j = jp[g], i = ip[g];
  float pjx = pos[3*j], pjy = pos[3*j+1], pjz = pos[3*j+2];
  float pix = pos[3*i], piy = pos[3*i+1], piz = pos[3*i+2];
  float vx = pjx-pix, vy = pjy-piy, vz = pjz-piz;
  float d = sqrtf(vx*vx + vy*vy + vz*vz);
  float inv = RCPF(d + 1e-10f);
  float edx = vx*inv, edy = vy*inv, edz = vz*inv;
  edb[3*el]=edx; edb[3*el+1]=edy; edb[3*el+2]=edz;
  if (ecv){
    float cx = piy*pjz - piz*pjy;
    float cy = piz*pjx - pix*pjz;
    float cz = pix*pjy - piy*pjx;
    float cn = sqrtf(cx*cx + cy*cy + cz*cz);
    float inv2 = RCPF(cn + 1e-10f);
    cx *= inv2; cy *= inv2; cz *= inv2;
    ecv[6*el]=cx; ecv[6*el+1]=cy; ecv[6*el+2]=cz;
    ecv[6*el+3]=edy*cz - edz*cy;
    ecv[6*el+4]=edz*cx - edx*cz;
    ecv[6*el+5]=edx*cy - edy*cx;
  }
  float rbv = 0.5f*(COSR(d*0.08333333333f) + 1.f);   // cos(d*pi/6)
  rb[el] = rbv;
  float env = (d < 6.f) ? rbv : 0.f;
  const float stf = 0.0024787522f;
  const float prf = (2.0f/96.0f)*(1.0f - stf);
  const float betaL = LOG2E/(prf*prf);
  float emd = EXP2F(-LOG2E*d);
  for (int k = 0; k < NRAD; ++k){
    float mu = stf + (1.0f - stf)*((float)k*(1.0f/95.0f));
    float t = emd - mu;
    remb[(size_t)el*NRAD + k] = f2b(env * EXP2F(-betaL*t*t));
  }
}

// ---------------- node embedding + layernorm (+ fused accumulator zeroing) ----------------
__global__ __launch_bounds__(128) void k_embed(const int* __restrict__ z,
    const float* __restrict__ ne_w, const float* __restrict__ ne_b,
    float* __restrict__ s, float* __restrict__ h0,
    float* __restrict__ S, float* __restrict__ vecacc)
{
  int n = blockIdx.x; int h = threadIdx.x;
  float x = ne_w[(size_t)z[n]*HIDDIM + h] + ne_b[h];
  __shared__ float red[128];
  red[h] = x; __syncthreads();
  for (int o = 64; o > 0; o >>= 1){ if (h < o) red[h] += red[h+o]; __syncthreads(); }
  float mean = red[0] * (1.f/128.f);
  __syncthreads();
  float dx = x - mean;
  red[h] = dx*dx; __syncthreads();
  for (int o = 64; o > 0; o >>= 1){ if (h < o) red[h] += red[h+o]; __syncthreads(); }
  float var = red[0] * (1.f/128.f);
  float y = dx * rsqrtf(var + 1e-5f);
  s[(size_t)n*HIDDIM + h] = y;
  h0[(size_t)n*HIDDIM + h] = y;
  float* Sr = &S[(size_t)n*384 + h];
  float* Vr = &vecacc[(size_t)n*384 + h];
  Sr[0]=0.f; Sr[128]=0.f; Sr[256]=0.f;
  Vr[0]=0.f; Vr[128]=0.f; Vr[256]=0.f;
}

// LN -> xln_b, plus fused s -> sb conversion
__global__ __launch_bounds__(128) void k_ln(const float* __restrict__ src, ushortT* __restrict__ dst,
    const float* __restrict__ g, const float* __restrict__ b, ushortT* __restrict__ sb)
{
  int n = blockIdx.x; int h = threadIdx.x;
  float x = src[(size_t)n*HIDDIM + h];
  sb[(size_t)n*HIDDIM + h] = f2b(x);
  __shared__ float red[128];
  red[h] = x; __syncthreads();
  for (int o = 64; o > 0; o >>= 1){ if (h < o) red[h] += red[h+o]; __syncthreads(); }
  float mean = red[0] * (1.f/128.f);
  __syncthreads();
  float dx = x - mean;
  red[h] = dx*dx; __syncthreads();
  for (int o = 64; o > 0; o >>= 1){ if (h < o) red[h] += red[h+o]; __syncthreads(); }
  float var = red[0] * (1.f/128.f);
  float y = dx * rsqrtf(var + 1e-5f);
  dst[(size_t)n*HIDDIM + h] = f2b(y * g[h] + b[h]);
}

// ---------------- rowptr-based segment sums (one block per node) ----------------
__global__ __launch_bounds__(128) void k_seg1n(const int* __restrict__ rowptr,
    const int* __restrict__ jp, int o, int Cc,
    const float* __restrict__ h0, const ushortT* __restrict__ rhid,
    float* __restrict__ s)
{
  int i = blockIdx.x, h = threadIdx.x;
  int b = rowptr[i], e = rowptr[i+1];
  if (b < o) b = o;
  int hi = o + Cc; if (e > hi) e = hi;
  if (b >= e) return;
  float acc = 0.f;
  int m = b;
  for (; m + 1 < e; m += 2){
    int j0 = jp[m], j1 = jp[m+1];
    float r0 = b2f(rhid[(size_t)(m-o)*HIDDIM + h]);
    float r1 = b2f(rhid[(size_t)(m+1-o)*HIDDIM + h]);
    acc += h0[(size_t)j0*HIDDIM + h]*r0 + h0[(size_t)j1*HIDDIM + h]*r1;
  }
  if (m < e) acc += h0[(size_t)jp[m]*HIDDIM + h] * b2f(rhid[(size_t)(m-o)*HIDDIM + h]);
  s[(size_t)i*HIDDIM + h] += acc;
}

__global__ __launch_bounds__(128) void k_seg2n(const int* __restrict__ rowptr,
    const int* __restrict__ jp, int o, int Cc,
    const ushortT* __restrict__ slin, const ushortT* __restrict__ rhid,
    const float* __restrict__ edb, float* __restrict__ S)
{
  int i = blockIdx.x, h = threadIdx.x;
  int b = rowptr[i], e = rowptr[i+1];
  if (b < o) b = o;
  int hi = o + Cc; if (e > hi) e = hi;
  if (b >= e) return;
  float a0 = 0.f, a1 = 0.f, a2 = 0.f;
  int m = b;
  for (; m + 1 < e; m += 2){
    int ml = m - o, ml2 = ml + 1;
    float u0 = b2f(slin[(size_t)jp[m]*HIDDIM + h])   * b2f(rhid[(size_t)ml*HIDDIM + h]);
    float u1 = b2f(slin[(size_t)jp[m+1]*HIDDIM + h]) * b2f(rhid[(size_t)ml2*HIDDIM + h]);
    a0 += u0*edb[3*ml]   + u1*edb[3*ml2];
    a1 += u0*edb[3*ml+1] + u1*edb[3*ml2+1];
    a2 += u0*edb[3*ml+2] + u1*edb[3*ml2+2];
  }
  if (m < e){
    int ml = m - o;
    float u0 = b2f(slin[(size_t)jp[m]*HIDDIM + h]) * b2f(rhid[(size_t)ml*HIDDIM + h]);
    a0 += u0*edb[3*ml]; a1 += u0*edb[3*ml+1]; a2 += u0*edb[3*ml+2];
  }
  float* base = &S[(size_t)i*384 + h];
  base[0]   += a0;
  base[128] += a1;
  base[256] += a2;
}

__global__ __launch_bounds__(128) void k_seg3n(const int* __restrict__ rowptr,
    int o, int Cc,
    const ushortT* __restrict__ mb, const float* __restrict__ edb,
    float* __restrict__ s, float* __restrict__ vecacc)
{
  int i = blockIdx.x, h = threadIdx.x;
  int b = rowptr[i], e = rowptr[i+1];
  if (b < o) b = o;
  int hi = o + Cc; if (e > hi) e = hi;
  if (b >= e) return;
  const float is128 = 0.08838834764831845f;
  float am = 0.f, v0 = 0.f, v1 = 0.f, v2 = 0.f;
  int m = b;
  for (; m + 1 < e; m += 2){
    int ml = m - o, ml2 = ml + 1;
    float m1a = b2f(mb[(size_t)ml*384 + h]);
    float m1b = b2f(mb[(size_t)ml2*384 + h]);
    float mma = b2f(mb[(size_t)ml*384 + 256 + h]) * is128;
    float mmb = b2f(mb[(size_t)ml2*384 + 256 + h]) * is128;
    am += m1a + m1b;
    v0 += mma*edb[3*ml]   + mmb*edb[3*ml2];
    v1 += mma*edb[3*ml+1] + mmb*edb[3*ml2+1];
    v2 += mma*edb[3*ml+2] + mmb*edb[3*ml2+2];
  }
  if (m < e){
    int ml = m - o;
    float m1 = b2f(mb[(size_t)ml*384 + h]);
    float mm = b2f(mb[(size_t)ml*384 + 256 + h]) * is128;
    am += m1;
    v0 += mm*edb[3*ml]; v1 += mm*edb[3*ml+1]; v2 += mm*edb[3*ml+2];
  }
  s[(size_t)i*HIDDIM + h] += am;
  float* base = &vecacc[(size_t)i*384 + h];
  base[0]   += v0;
  base[128] += v1;
  base[256] += v2;
}

// ---------------- scalarize v4: 2 edges/block, no LDS, scalar weights ----------------
// writes only scal values (256/edge) to ews (stride 256)
__global__ __launch_bounds__(256) void k_scal4(
  const int* __restrict__ jp, const int* __restrict__ ip, int off, int Cc,
  const float* __restrict__ S,
  const float* __restrict__ edb, const float* __restrict__ ecv,
  const float* __restrict__ rb,
  const float* __restrict__ l3s,
  ushortT* __restrict__ ews)
{
  int ea = blockIdx.x*2;
  int eb = (ea + 1 < Cc) ? ea + 1 : ea;
  int t = threadIdx.x;
  int which = t >> 7, h = t & 127;
  int ga = off + ea, gb = off + eb;
  int na = which ? jp[ga] : ip[ga];
  int nb = which ? jp[gb] : ip[gb];
  f2_t f00 = {edb[3*ea],   edb[3*eb]};
  f2_t f01 = {edb[3*ea+1], edb[3*eb+1]};
  f2_t f02 = {edb[3*ea+2], edb[3*eb+2]};
  f2_t f10 = {ecv[6*ea],   ecv[6*eb]};
  f2_t f11 = {ecv[6*ea+1], ecv[6*eb+1]};
  f2_t f12 = {ecv[6*ea+2], ecv[6*eb+2]};
  f2_t f20 = {ecv[6*ea+3], ecv[6*eb+3]};
  f2_t f21 = {ecv[6*ea+4], ecv[6*eb+4]};
  f2_t f22 = {ecv[6*ea+5], ecv[6*eb+5]};
  f2_t rbv = {rb[ea], rb[eb]};
  const float* Sa = &S[(size_t)na*384];
  const float* Sb = &S[(size_t)nb*384];
  f2_t S0 = {Sa[h],     Sb[h]};
  f2_t S1 = {Sa[128+h], Sb[128+h]};
  f2_t S2 = {Sa[256+h], Sb[256+h]};
  f2_t v0 = S0*f00 + S1*f01 + S2*f02;
  f2_t v1t = S0*f10 + S1*f11 + S2*f12;
  f2_t v1 = {fabsf(v1t.x), fabsf(v1t.y)};
  f2_t v2 = S0*f20 + S1*f21 + S2*f22;
  f2_t out = {0.f, 0.f};
  #pragma unroll
  for (int u = 0; u < 32; ++u){
    f2_t tt = v0*l3s[u] + v1*l3s[32+u] + v2*l3s[64+u] + l3s[96+u];
    f2_t r;
    r.x = RCPF(1.f + EXP2F(tt.x));
    r.y = RCPF(1.f + EXP2F(tt.y));
    out += (tt*r)*l3s[128+u];
  }
  f2_t res = (out + l3s[160] + v0) * rbv;
  ews[(size_t)ea*256 + which*128 + h] = f2b(res.x);
  if (eb != ea) ews[(size_t)eb*256 + which*128 + h] = f2b(res.y);
}

// ---------------- bf16 MFMA GEMM ----------------
// A: MxK bf16 row-major; BT: NxK bf16 row-major. N%128==0, K%32==0.
// epi: 0 none, 1 silu, 2 *rowscale[row], 3 *mul1b[row,col]*xhpb[jidx[row],col]
// skipTile >= 0: that 128-col tile is not computed (grid.x one smaller).
// A1 != nullptr: split-A — K [0,256) from A (stride 256), [256,384) from A1
// (stride 128), [384,480) from A2 (stride 96).
__global__ __launch_bounds__(256) void mgemm(
  const ushortT* __restrict__ A, const ushortT* __restrict__ BT,
  const float* __restrict__ bias,
  float* __restrict__ Cf, ushortT* __restrict__ Cb,
  int M, int N, int K, int epi,
  const float* __restrict__ rowscale,
  const ushortT* __restrict__ mul1b,
  const ushortT* __restrict__ xhpb,
  const int* __restrict__ jidx,
  int skipTile,
  const ushortT* __restrict__ A1, const ushortT* __restrict__ A2)
{
  const int tid = threadIdx.x;
  const int w = tid >> 6;
  const int lane = tid & 63;
  const int l15 = lane & 15;
  const int q = lane >> 4;
  const int wm = w & 1, wn = w >> 1;
  const int rowBase = blockIdx.y * 128;
  int bx = blockIdx.x;
  if (skipTile >= 0 && bx >= skipTile) bx++;
  const int colBase = bx * 128;
  f4_t acc[4][4] = {};

#ifdef HAVE_GLDS
  __shared__ ushortT As[128*32];
  __shared__ ushortT Bs[128*32];
  const int rS = 32*w + (lane >> 2);
  const int kS = (lane & 3) << 3;
  ushortT* lA0 = &As[(32*w)*32];
  ushortT* lA1 = &As[(32*w+16)*32];
  ushortT* lB0 = &Bs[(32*w)*32];
  ushortT* lB1 = &Bs[(32*w+16)*32];
  int ra0 = rowBase + rS;      if (ra0 >= M) ra0 = M-1;
  int ra1 = rowBase + rS + 16; if (ra1 >= M) ra1 = M-1;
  const ushortT* gB0 = BT + (size_t)(colBase + rS)*K + kS;
  const ushortT* gB1 = BT + (size_t)(colBase + rS + 16)*K + kS;
  for (int k0 = 0; k0 < K; k0 += 32){
    const ushortT* srcA; size_t strA; int kc;
    if (!A1){ srcA = A; strA = (size_t)K; kc = k0; }
    else if (k0 < 256){ srcA = A; strA = 256; kc = k0; }
    else if (k0 < 384){ srcA = A1; strA = 128; kc = k0 - 256; }
    else { srcA = A2; strA = 96; kc = k0 - 384; }
    glds16(srcA + (size_t)ra0*strA + kc + kS, lA0);
    glds16(srcA + (size_t)ra1*strA + kc + kS, lA1);
    glds16(gB0 + k0, lB0);
    glds16(gB1 + k0, lB1);
    __syncthreads();
    bf8_t a[4], b[4];
    #pragma unroll
    for (int mt = 0; mt < 4; ++mt)
      a[mt] = *(const bf8_t*)&As[(wm*64 + mt*16 + l15)*32 + q*8];
    #pragma unroll
    for (int nt = 0; nt < 4; ++nt)
      b[nt] = *(const bf8_t*)&Bs[(wn*64 + nt*16 + l15)*32 + q*8];
    #pragma unroll
    for (int mt = 0; mt < 4; ++mt){
      #pragma unroll
      for (int nt = 0; nt < 4; ++nt)
        acc[mt][nt] = __builtin_amdgcn_mfma_f32_16x16x32_bf16(a[mt], b[nt], acc[mt][nt], 0, 0, 0);
    }
    __syncthreads();
  }
#else
  __shared__ ushortT As[128*48];
  __shared__ ushortT Bs[128*48];
  const int r0 = tid >> 2,         s0 = (tid & 3) << 3;
  const int r1 = (tid + 256) >> 2, s1 = ((tid + 256) & 3) << 3;
  for (int k0 = 0; k0 < K; k0 += 32){
    const ushortT* srcA; size_t strA; int kc;
    if (!A1){ srcA = A; strA = (size_t)K; kc = k0; }
    else if (k0 < 256){ srcA = A; strA = 256; kc = k0; }
    else if (k0 < 384){ srcA = A1; strA = 128; kc = k0 - 256; }
    else { srcA = A2; strA = 96; kc = k0 - 384; }
    int4 a0v = make_int4(0,0,0,0), a1v = make_int4(0,0,0,0);
    if (rowBase + r0 < M) a0v = *(const int4*)&srcA[(size_t)(rowBase + r0)*strA + kc + s0];
    if (rowBase + r1 < M) a1v = *(const int4*)&srcA[(size_t)(rowBase + r1)*strA + kc + s1];
    int4 b0v = *(const int4*)&BT[(size_t)(colBase + r0)*K + k0 + s0];
    int4 b1v = *(const int4*)&BT[(size_t)(colBase + r1)*K + k0 + s1];
    __syncthreads();
    *(int4*)&As[r0*48 + s0] = a0v;
    *(int4*)&As[r1*48 + s1] = a1v;
    *(int4*)&Bs[r0*48 + s0] = b0v;
    *(int4*)&Bs[r1*48 + s1] = b1v;
    __syncthreads();
    bf8_t a[4], b[4];
    #pragma unroll
    for (int mt = 0; mt < 4; ++mt)
      a[mt] = *(const bf8_t*)&As[(wm*64 + mt*16 + l15)*48 + q*8];
    #pragma unroll
    for (int nt = 0; nt < 4; ++nt)
      b[nt] = *(const bf8_t*)&Bs[(wn*64 + nt*16 + l15)*48 + q*8];
    #pragma unroll
    for (int mt = 0; mt < 4; ++mt){
      #pragma unroll
      for (int nt = 0; nt < 4; ++nt)
        acc[mt][nt] = __builtin_amdgcn_mfma_f32_16x16x32_bf16(a[mt], b[nt], acc[mt][nt], 0, 0, 0);
    }
  }
#endif

  #pragma unroll
  for (int mt = 0; mt < 4; ++mt){
    int row = rowBase + wm*64 + mt*16 + q*4;
    #pragma unroll
    for (int nt = 0; nt < 4; ++nt){
      int col = colBase + wn*64 + nt*16 + l15;
      float bv = bias ? bias[col] : 0.f;
      #pragma unroll
      for (int r = 0; r < 4; ++r){
        int rr = row + r;
        if (rr >= M) continue;
        float x = acc[mt][nt][r] + bv;
        if (epi == 1) x = silu_f(x);
        else if (epi == 2) x *= rowscale[rr];
        else if (epi == 3) x = x * b2f(mul1b[(size_t)rr*N + col]) * b2f(xhpb[(size_t)jidx[rr]*N + col]);
        if (Cb) Cb[(size_t)rr*N + col] = f2b(x);
        else    Cf[(size_t)rr*N + col] = x;
      }
    }
  }
}

// ---------------- fte prep ----------------
__global__ __launch_bounds__(128) void k_fte_pre(const float* __restrict__ vpc,
    const float* __restrict__ s, ushortT* __restrict__ catb, float* __restrict__ vdot,
    int no)
{
  int nl = blockIdx.x, h = threadIdx.x;
  int n = no + nl;
  const float* base = &vpc[(size_t)nl*768];
  float a0 = base[h],       a1 = base[256+h],     a2 = base[512+h];
  float c0 = base[128+h],   c1 = base[384+h],     c2 = base[640+h];
  float scal = sqrtf(a0*a0 + a1*a1 + a2*a2 + 1e-10f);
  float vd = (a0*c0 + a1*c1 + a2*c2) * 0.08838834764831845f;
  catb[(size_t)n*256 + h] = f2b(s[(size_t)n*HIDDIM + h]);
  catb[(size_t)n*256 + 128 + h] = f2b(scal);
  vdot[(size_t)n*HIDDIM + h] = vd;
}

// ---------------- final ----------------
__global__ __launch_bounds__(128) void k_out(const float* __restrict__ xh2,
    const float* __restrict__ vdot, const float* __restrict__ s,
    const float* __restrict__ ow, const float* __restrict__ ob,
    float* __restrict__ nodeout)
{
  int n = blockIdx.x, h = threadIdx.x;
  float a1 = xh2[(size_t)n*384 + h];
  float a2 = xh2[(size_t)n*384 + 128 + h];
  float sv = s[(size_t)n*HIDDIM + h] + (a1 + a2*vdot[(size_t)n*HIDDIM + h]) * 0.7071067811865476f;
  __shared__ float red[128];
  red[h] = sv * ow[h];
  __syncthreads();
  for (int o = 64; o > 0; o >>= 1){ if (h < o) red[h] += red[h+o]; __syncthreads(); }
  if (h == 0) nodeout[n] = red[0] + ob[0];
}

__global__ __launch_bounds__(256) void k_final(const float* __restrict__ nodeout,
    const int* __restrict__ batch, void* __restrict__ out, int Nn, const int* flags)
{
  int g = blockIdx.x;
  __shared__ float rs[256], rc[256];
  float sm = 0.f, c = 0.f;
  for (int n = threadIdx.x; n < Nn; n += 256){
    if (batch[n] == g){ sm += nodeout[n]; c += 1.f; }
  }
  rs[threadIdx.x] = sm; rc[threadIdx.x] = c;
  __syncthreads();
  for (int o = 128; o > 0; o >>= 1){
    if (threadIdx.x < o){ rs[threadIdx.x] += rs[threadIdx.x+o]; rc[threadIdx.x] += rc[threadIdx.x+o]; }
    __syncthreads();
  }
  if (threadIdx.x == 0){
    float v = (rc[0] > 0.f) ? rs[0]/rc[0] : 0.f;
    if (flags[2] == 0) ((__hip_bfloat16*)out)[g] = __float2bfloat16(v);
    else ((float*)out)[g] = v;
  }
}

// =====================================================================
extern "C" void kernel_launch(void* const* d_in, const int* in_sizes, int n_in,
                              void* d_out, int out_size, void* d_ws, size_t ws_size,
                              hipStream_t stream)
{
  const int N = in_sizes[0] / 3;
  const int E = in_sizes[3] / 2;

  size_t off = 0;
  auto alloc = [&](size_t n)->float*{
    float* p = (float*)d_ws + off;
    off += (n + 3) & ~(size_t)3;
    return p;
  };
  auto allocU = [&](size_t n)->ushortT*{ return (ushortT*)alloc((n + 1) / 2); };

  int* flags  = (int*)alloc(4);
  int* deg    = (int*)alloc((size_t)N);
  int* cursor = (int*)alloc((size_t)N);
  size_t zeroHdr = off;
  int* zi     = (int*)alloc((size_t)N);
  int* bi     = (int*)alloc((size_t)N);
  int* eii    = (int*)alloc((size_t)2*E);
  int* rowptr = (int*)alloc((size_t)N + 4);
  int* jp     = (int*)alloc((size_t)E);
  int* ipp    = (int*)alloc((size_t)E);
  float* l3s  = alloc(164);

  float* pos = alloc((size_t)N*3);
  float* w[31];
  for (int t = 0; t < 31; ++t) w[t] = alloc((size_t)in_sizes[4+t]);
  float* rl_b1=w[1];  float* rl_b2=w[3];
  float* ne_w =w[4];  float* ne_b =w[5];  float* sv_b =w[7];
  float* l3_w1=w[8];  float* l3_b1=w[9];  float* l3_w2=w[10]; float* l3_b2=w[11];
  float* mp_w =w[12]; float* mp_b =w[13]; float* xp_b1=w[15];
  float* xp_b2=w[17]; float* rp_b =w[19];
  float* ip_b1=w[21]; float* ip_b2=w[23];
  float* fte_b1=w[26];float* fte_b2=w[28];float* out_w=w[29]; float* out_b=w[30];

  ushortT* wt_rl1 = allocU(96*128);
  ushortT* wt_rl2 = allocU(128*128);
  ushortT* wt_sv  = allocU(128*128);
  ushortT* wt_xp1 = allocU(128*128);
  ushortT* wt_xp2 = allocU((size_t)128*384);
  ushortT* wt_rp  = allocU((size_t)96*384);
  ushortT* wt_ip1 = allocU((size_t)480*384);
  ushortT* wt_ip2 = allocU((size_t)384*384);
  ushortT* wt_feq = allocU((size_t)128*256);
  ushortT* wt_ft1 = allocU((size_t)256*128);
  ushortT* wt_ft2 = allocU((size_t)128*384);

  float* s    = alloc((size_t)N*HIDDIM);
  float* h0   = alloc((size_t)N*HIDDIM);      // -> vdot overlay after seg1
  ushortT* sb     = allocU((size_t)N*HIDDIM); // sb+slin_b contiguous -> catb overlay
  ushortT* slin_b = allocU((size_t)N*HIDDIM);
  ushortT* xln_b  = allocU((size_t)N*HIDDIM);
  ushortT* hb     = allocU((size_t)N*HIDDIM);
  float* S    = alloc((size_t)N*384);         // -> vab overlay in phase F
  float* vecacc = alloc((size_t)N*384);       // -> xh2 overlay after f2b
  ushortT* xh_b = allocU((size_t)N*384);
  float* nodeout = alloc((size_t)N);
  float* vdot = h0;
  ushortT* catb = sb;
  ushortT* vab = (ushortT*)S;
  float* xh2 = vecacc;

  size_t wsF = ws_size / sizeof(float);

  // tier selection:
  //  tier2: persist edb(3)+ecv(6)+rb(1)+remb(48)+rhid(64) = 122 f/edge; chunk 576 f/edge
  //  tier1: persist edb+rhid (67 f/edge);                  chunk 631 f/edge
  //  tier0: nothing persists;                              chunk 698 f/edge
  int tier = 0; size_t p = 698;
  if (off + 122ULL*(size_t)E + 16 + 256ULL*576 <= wsF){ tier = 2; p = 576; }
  else if (off + 67ULL*(size_t)E + 16 + 256ULL*631 <= wsF){ tier = 1; p = 631; }

  ushortT *rhid_a = nullptr, *remb_a = nullptr;
  float *edb_a = nullptr, *ecv_a = nullptr, *rb_a = nullptr;
  if (tier >= 1){
    rhid_a = allocU((size_t)E*128);
    edb_a  = alloc((size_t)3*E);
  }
  if (tier == 2){
    ecv_a  = alloc((size_t)6*E);
    rb_a   = alloc((size_t)E);
    remb_a = allocU((size_t)E*96);
  }
  size_t availF = (wsF > off) ? (wsF - off) : 0;
  if (availF < 256*p){
    k_sentinel<<<1, 64, 0, stream>>>((__hip_bfloat16*)d_out, out_size,
                                     (float)(double)(ws_size >> 20));
    return;
  }
  size_t Cs = availF / p; if (Cs > (size_t)E) Cs = E;
  int C = (int)(Cs & ~(size_t)15);
  if (C < 256) C = 256;

  float* scratch0 = (float*)d_ws + off;
  ushortT* remb_l = nullptr; float *ecv_l = nullptr, *rb_l = nullptr;
  if (tier <= 1){
    remb_l = allocU((size_t)C*96);   // 48C
    ecv_l  = alloc((size_t)6*C);
    rb_l   = alloc((size_t)C);
  }
  float* edb_l = nullptr; ushortT* rhid_l = nullptr;
  if (tier == 0){
    edb_l  = alloc((size_t)3*C);
    rhid_l = allocU((size_t)C*128);
  }
  ushortT* ewReg = allocU((size_t)C*384);     // 192C: ews (256/edge) then Rmb (384/edge)
  ushortT* R2b  = allocU((size_t)C*384);      // 192C ; R2rl overlays
  ushortT* R1b  = allocU((size_t)C*384);      // 192C
  ushortT* ews  = ewReg;
  ushortT* Rmb  = ewReg;
  ushortT* R2rl = R2b;
  float* vpc = scratch0;
  size_t scratchF = (size_t)C*p;

  auto mg = [&](const ushortT* A, const ushortT* BT, const float* bias,
                float* Cf, ushortT* Cb, int M, int Nc, int K, int epi,
                const float* rowscale = nullptr, const ushortT* mul1b = nullptr,
                const ushortT* xhpb = nullptr, const int* jidx = nullptr,
                int skipTile = -1,
                const ushortT* A1 = nullptr, const ushortT* A2 = nullptr){
    dim3 grid(Nc/128 - (skipTile >= 0 ? 1 : 0), (M + 127)/128);
    mgemm<<<grid, 256, 0, stream>>>(A, BT, bias, Cf, Cb, M, Nc, K, epi,
                                    rowscale, mul1b, xhpb, jidx, skipTile, A1, A2);
  };

  // 0) zero header, detect dtypes, int-normalize (+deg histogram)
  k_zero<<<64, 256, 0, stream>>>((float*)flags, (int)zeroHdr);
  k_detect<<<64, 256, 0, stream>>>((const ushortT*)d_in[0], in_sizes[0],
                                   (const int*)d_in[2], in_sizes[2], flags);
  k_iconv<<<1024, 256, 0, stream>>>((const int*)d_in[1], (const int*)d_in[2],
                                    (const int*)d_in[3], zi, bi, eii, N, E, flags, deg);

  // 1) float conversions + transposed bf16 weights + l3 prescale
  ConvArgs ca;
  ca.d[0] = { (const ushortT*)d_in[0], pos, in_sizes[0] };
  for (int t = 0; t < 31; ++t)
    ca.d[1+t] = { (const ushortT*)d_in[4+t], w[t], in_sizes[4+t] };
  k_conv<<<dim3(32, 32), 256, 0, stream>>>(ca, 32, flags);
  k_l3pre<<<1, 192, 0, stream>>>(l3_w1, l3_b1, l3_w2, l3_b2, l3s);

  TArgs ta;
  ta.d[0]  = { (const ushortT*)d_in[4],  wt_rl1, 96, 128 };
  ta.d[1]  = { (const ushortT*)d_in[6],  wt_rl2, 128, 128 };
  ta.d[2]  = { (const ushortT*)d_in[10], wt_sv,  128, 128 };
  ta.d[3]  = { (const ushortT*)d_in[18], wt_xp1, 128, 128 };
  ta.d[4]  = { (const ushortT*)d_in[20], wt_xp2, 128, 384 };
  ta.d[5]  = { (const ushortT*)d_in[22], wt_rp,  96, 384 };
  ta.d[6]  = { (const ushortT*)d_in[24], wt_ip1, 480, 384 };
  ta.d[7]  = { (const ushortT*)d_in[26], wt_ip2, 384, 384 };
  ta.d[8]  = { (const ushortT*)d_in[28], wt_feq, 128, 256 };
  ta.d[9]  = { (const ushortT*)d_in[29], wt_ft1, 256, 128 };
  ta.d[10] = { (const ushortT*)d_in[31], wt_ft2, 128, 384 };
  k_wt<<<dim3(48, 11), 256, 0, stream>>>(ta, 11, flags);

  // 2) CSR scan + scatter
  k_csr_scan<<<1, 256, 0, stream>>>(deg, rowptr, N);
  k_csr_scatter<<<(E + 255)/256, 256, 0, stream>>>(eii, E, rowptr, cursor, jp, ipp);

  // 3) node embedding (+ S/vecacc zero fused)
  k_embed<<<N, 128, 0, stream>>>(zi, ne_w, ne_b, s, h0, S, vecacc);

  // pre-pass + Phase B
  if (tier == 2){
    k_geom<<<(E + 255)/256, 256, 0, stream>>>(pos, jp, ipp, 0, E,
                                              edb_a, ecv_a, rb_a, remb_a);
    for (int o = 0; o < E; o += C){
      int Cc = (E - o < C) ? (E - o) : C;
      mg(remb_a + (size_t)o*96, wt_rl1, rl_b1, nullptr, R2rl, Cc, 128, 96, 1);
      mg(R2rl, wt_rl2, rl_b2, nullptr, rhid_a + (size_t)o*128, Cc, 128, 128, 2, rb_a + o);
    }
    k_seg1n<<<N, 128, 0, stream>>>(rowptr, jp, 0, E, h0, rhid_a, s);
  } else if (tier == 1){
    for (int o = 0; o < E; o += C){
      int Cc = (E - o < C) ? (E - o) : C;
      k_geom<<<(Cc + 255)/256, 256, 0, stream>>>(pos, jp, ipp, o, Cc,
                                                 edb_a + (size_t)3*o, nullptr, rb_l, remb_l);
      mg(remb_l, wt_rl1, rl_b1, nullptr, R2rl, Cc, 128, 96, 1);
      mg(R2rl, wt_rl2, rl_b2, nullptr, rhid_a + (size_t)o*128, Cc, 128, 128, 2, rb_l);
    }
    k_seg1n<<<N, 128, 0, stream>>>(rowptr, jp, 0, E, h0, rhid_a, s);
  } else {
    for (int o = 0; o < E; o += C){
      int Cc = (E - o < C) ? (E - o) : C;
      k_geom<<<(Cc + 255)/256, 256, 0, stream>>>(pos, jp, ipp, o, Cc,
                                                 edb_l, nullptr, rb_l, remb_l);
      mg(remb_l, wt_rl1, rl_b1, nullptr, R2rl, Cc, 128, 96, 1);
      mg(R2rl, wt_rl2, rl_b2, nullptr, rhid_l, Cc, 128, 128, 2, rb_l);
      k_seg1n<<<N, 128, 0, stream>>>(rowptr, jp, o, Cc, h0, rhid_l, s);
    }
  }

  // Phase C: slin, xln(+sb), xh (xh cols 128-255 dead -> skip tile 1)
  k_ln<<<N, 128, 0, stream>>>(s, xln_b, mp_w, mp_b, sb);
  mg(sb, wt_sv, sv_b, nullptr, slin_b, N, 128, 128, 1);
  mg(xln_b, wt_xp1, xp_b1, nullptr, hb, N, 128, 128, 1);
  mg(hb, wt_xp2, xp_b2, nullptr, xh_b, N, 384, 128, 0, nullptr, nullptr, nullptr, nullptr, 1);

  // Phase D: seg2
  if (tier >= 1){
    k_seg2n<<<N, 128, 0, stream>>>(rowptr, jp, 0, E, slin_b, rhid_a, edb_a, S);
  } else {
    for (int o = 0; o < E; o += C){
      int Cc = (E - o < C) ? (E - o) : C;
      k_geom<<<(Cc + 255)/256, 256, 0, stream>>>(pos, jp, ipp, o, Cc,
                                                 edb_l, nullptr, rb_l, remb_l);
      mg(remb_l, wt_rl1, rl_b1, nullptr, R2rl, Cc, 128, 96, 1);
      mg(R2rl, wt_rl2, rl_b2, nullptr, rhid_l, Cc, 128, 128, 2, rb_l);
      k_seg2n<<<N, 128, 0, stream>>>(rowptr, jp, o, Cc, slin_b, rhid_l, edb_l, S);
    }
  }

  // Phase E: per-edge big MLPs + seg3 (rp/ip2 skip dead middle tile; ip1 split-A)
  for (int o = 0; o < E; o += C){
    int Cc = (E - o < C) ? (E - o) : C;
    const ushortT *rhid_p, *remb_p;
    const float *edb_p, *ecv_p, *rb_p;
    if (tier == 2){
      rhid_p = rhid_a + (size_t)o*128;
      edb_p  = edb_a + (size_t)3*o;
      ecv_p  = ecv_a + (size_t)6*o;
      rb_p   = rb_a + o;
      remb_p = remb_a + (size_t)o*96;
    } else if (tier == 1){
      k_geom<<<(Cc + 255)/256, 256, 0, stream>>>(pos, jp, ipp, o, Cc,
                                                 edb_a + (size_t)3*o, ecv_l, rb_l, remb_l);
      rhid_p = rhid_a + (size_t)o*128;
      edb_p  = edb_a + (size_t)3*o;
      ecv_p  = ecv_l; rb_p = rb_l; remb_p = remb_l;
    } else {
      k_geom<<<(Cc + 255)/256, 256, 0, stream>>>(pos, jp, ipp, o, Cc,
                                                 edb_l, ecv_l, rb_l, remb_l);
      mg(remb_l, wt_rl1, rl_b1, nullptr, R2rl, Cc, 128, 96, 1);
      mg(R2rl, wt_rl2, rl_b2, nullptr, rhid_l, Cc, 128, 128, 2, rb_l);
      rhid_p = rhid_l; edb_p = edb_l; ecv_p = ecv_l; rb_p = rb_l; remb_p = remb_l;
    }
    k_scal4<<<(Cc + 1)/2, 256, 0, stream>>>(jp, ipp, o, Cc, S,
                                            edb_p, ecv_p, rb_p, l3s, ews);
    mg(remb_p, wt_rp, rp_b, nullptr, R1b, Cc, 384, 96, 0,
       nullptr, nullptr, nullptr, nullptr, 1);
    mg(ews, wt_ip1, ip_b1, nullptr, R2b, Cc, 384, 480, 1,
       nullptr, nullptr, nullptr, nullptr, -1, rhid_p, remb_p);
    mg(R2b, wt_ip2, ip_b2, nullptr, Rmb, Cc, 384, 384, 3,
       nullptr, R1b, xh_b, jp + o, 1);
    k_seg3n<<<N, 128, 0, stream>>>(rowptr, o, Cc, Rmb, edb_p, s, vecacc);
  }

  // Phase F: fte
  k_f2b<<<1024, 256, 0, stream>>>(vecacc, vab, N*384);
  int Cn = (int)(scratchF / 768);
  if (Cn > N) Cn = N;
  for (int no = 0; no < N; no += Cn){
    int Cc = (N - no < Cn) ? (N - no) : Cn;
    mg(vab + (size_t)no*384, wt_feq, nullptr, vpc, nullptr, 3*Cc, 256, 128, 0);
    k_fte_pre<<<Cc, 128, 0, stream>>>(vpc, s, catb, vdot, no);
  }
  mg(catb, wt_ft1, fte_b1, nullptr, hb, N, 128, 256, 1);
  mg(hb, wt_ft2, fte_b2, xh2, nullptr, N, 384, 128, 0);

  // Phase G
  k_out<<<N, 128, 0, stream>>>(xh2, vdot, s, out_w, out_b, nodeout);
  k_final<<<out_size, 256, 0, stream>>>(nodeout, bi, d_out, N, flags);
}

// Round 14
// 1664.348 us; speedup vs baseline: 1.9774x; 1.0922x over previous
//
#include <hip/hip_runtime.h>
#include <hip/hip_bf16.h>
#include <math.h>

#define NRAD 96
#define HIDDIM 128
typedef unsigned short ushortT;

typedef __attribute__((ext_vector_type(8))) short bf8_t;   // 8 bf16 (4 VGPRs)
typedef __attribute__((ext_vector_type(4))) float f4_t;    // 4 fp32 acc
typedef __attribute__((ext_vector_type(2))) float f2_t;    // packed fp32 pair

#if defined(__has_builtin)
#  if __has_builtin(__builtin_amdgcn_global_load_lds)
#    define HAVE_GLDS 1
#  endif
#  if __has_builtin(__builtin_amdgcn_rcpf)
#    define RCPF(x) __builtin_amdgcn_rcpf(x)
#  endif
#  if __has_builtin(__builtin_amdgcn_exp2f)
#    define EXP2F(x) __builtin_amdgcn_exp2f(x)
#  endif
#  if __has_builtin(__builtin_amdgcn_cosf)
#    define COSR(x) __builtin_amdgcn_cosf(x)   /* cos(2*pi*x) */
#  endif
#endif
#ifndef RCPF
#  define RCPF(x) (1.f/(x))
#endif
#ifndef EXP2F
#  define EXP2F(x) exp2f(x)
#endif
#ifndef COSR
#  define COSR(x) cosf(6.2831853071795864f*(x))
#endif
#define LOG2E 1.44269504088896f
#define LN2   0.69314718055995f

__device__ __forceinline__ float silu_f(float x){
  return x * RCPF(1.f + EXP2F(-LOG2E*x));
}
__device__ __forceinline__ float b2f(ushortT u){ return __uint_as_float(((unsigned int)u) << 16); }
__device__ __forceinline__ ushortT f2b(float x){
  unsigned int u = __float_as_uint(x);
  unsigned int r = (u + 0x7fffu + ((u >> 16) & 1u)) >> 16;
  return (ushortT)r;
}

#ifdef HAVE_GLDS
__device__ __forceinline__ void glds16(const ushortT* g, ushortT* l){
  __builtin_amdgcn_global_load_lds(
      (const __attribute__((address_space(1))) ushortT*)g,
      (__attribute__((address_space(3))) ushortT*)l, 16, 0, 0);
}
#endif

// ---------------- dtype detection (parallel) ----------------
__global__ void k_detect(const ushortT* posw, int npos,
                         const int* batchw, int nb, int* flags){
  int tot = (npos < 4096 ? npos : 4096);
  int big = tot > nb ? tot : nb;
  int bad = 0, orv = 0;
  for (int t = blockIdx.x*blockDim.x + threadIdx.x; t < big; t += gridDim.x*blockDim.x){
    if (t < tot){
      float x = b2f(posw[t]);
      if (!(fabsf(x) <= 1000.f)) bad = 1;
    }
    if (t < nb && (t & 1)) orv |= batchw[t];
  }
  if (bad) atomicOr(&flags[2], 1);
  if (orv) atomicOr(&flags[3], 1);
}

__global__ void k_iconv(const int* zsrc, const int* bsrc, const int* esrc,
                        int* zi, int* bi, int* eii, int Nn, int E, const int* flags,
                        int* deg){
  int f = (flags[3] == 0) ? 1 : 0;   // 1 => int64
  int total = 2*Nn + 2*E;
  for (int t = blockIdx.x*blockDim.x + threadIdx.x; t < total; t += gridDim.x*blockDim.x){
    if (t < Nn) zi[t] = zsrc[(size_t)t << f];
    else if (t < 2*Nn) bi[t-Nn] = bsrc[(size_t)(t-Nn) << f];
    else {
      int e = t - 2*Nn;
      int v = esrc[(size_t)e << f];
      eii[e] = v;
      if (e >= E) atomicAdd(&deg[v], 1);
    }
  }
}

// ---------------- conversion: (bf16|f32) -> f32 ----------------
struct ConvDesc { const ushortT* src; float* dst; int n; };
struct ConvArgs { ConvDesc d[32]; };

__global__ void k_conv(ConvArgs a, int cnt, const int* flags){
  int y = blockIdx.y;
  if (y >= cnt) return;
  int f = (flags[2] == 0) ? 1 : 0;    // 1 => bf16
  const ushortT* s = a.d[y].src;
  float* dst = a.d[y].dst;
  int n = a.d[y].n;
  if (f){
    for (int t = blockIdx.x*blockDim.x + threadIdx.x; t < n; t += gridDim.x*blockDim.x)
      dst[t] = b2f(s[t]);
  } else {
    const float* sf = (const float*)s;
    for (int t = blockIdx.x*blockDim.x + threadIdx.x; t < n; t += gridDim.x*blockDim.x)
      dst[t] = sf[t];
  }
}

// prescale l3 weights: [0,96) w1*-log2e, [96,128) b1*-log2e, [128,160) w2*-ln2, [160] b2
__global__ void k_l3pre(const float* __restrict__ w1, const float* __restrict__ b1,
                        const float* __restrict__ w2, const float* __restrict__ b2,
                        float* __restrict__ l3s){
  int t = threadIdx.x;
  if (t < 96) l3s[t] = w1[t] * (-LOG2E);
  else if (t < 128) l3s[t] = b1[t-96] * (-LOG2E);
  else if (t < 160) l3s[t] = w2[t-128] * (-LN2);
  else if (t == 160) l3s[160] = b2[0];
}

// ---------------- weight transpose -> bf16 [N][K] ----------------
struct TDesc { const ushortT* src; ushortT* dst; int K, N; };
struct TArgs { TDesc d[12]; };

__global__ void k_wt(TArgs a, int cnt, const int* flags){
  int y = blockIdx.y;
  if (y >= cnt) return;
  int f = (flags[2] == 0) ? 1 : 0;
  const ushortT* s = a.d[y].src;
  ushortT* dst = a.d[y].dst;
  int K = a.d[y].K, N = a.d[y].N, tot = K*N;
  for (int t = blockIdx.x*blockDim.x + threadIdx.x; t < tot; t += gridDim.x*blockDim.x){
    int k = t / N, n = t - k*N;
    ushortT v = f ? s[t] : f2b(((const float*)s)[t]);
    dst[(size_t)n*K + k] = v;
  }
}

__global__ void k_f2b(const float* __restrict__ src, ushortT* __restrict__ dst, int n){
  for (int t = blockIdx.x*blockDim.x + threadIdx.x; t < n; t += gridDim.x*blockDim.x)
    dst[t] = f2b(src[t]);
}

__global__ void k_zero(float* __restrict__ p, int n){
  int t = blockIdx.x*blockDim.x + threadIdx.x;
  int stride = gridDim.x*blockDim.x;
  for (; t < n; t += stride) p[t] = 0.f;
}

__global__ void k_sentinel(__hip_bfloat16* out, int n, float val){
  int t = threadIdx.x;
  if (t < n) out[t] = __float2bfloat16(val);
}

// ---------------- CSR scan + scatter ----------------
__global__ void k_csr_scan(const int* __restrict__ deg, int* __restrict__ rowptr, int Nn){
  __shared__ int sh[256];
  __shared__ int carry;
  if (threadIdx.x == 0){ carry = 0; rowptr[0] = 0; }
  __syncthreads();
  for (int t0 = 0; t0 < Nn; t0 += 256){
    int idx = t0 + threadIdx.x;
    int v = (idx < Nn) ? deg[idx] : 0;
    sh[threadIdx.x] = v; __syncthreads();
    for (int o = 1; o < 256; o <<= 1){
      int u = (threadIdx.x >= o) ? sh[threadIdx.x - o] : 0;
      __syncthreads();
      sh[threadIdx.x] += u; __syncthreads();
    }
    if (idx < Nn) rowptr[idx + 1] = carry + sh[threadIdx.x];
    __syncthreads();
    if (threadIdx.x == 0) carry += sh[255];
    __syncthreads();
  }
}

__global__ void k_csr_scatter(const int* __restrict__ eii, int E,
                              const int* __restrict__ rowptr, int* __restrict__ cursor,
                              int* __restrict__ jp, int* __restrict__ ip){
  int e = blockIdx.x*blockDim.x + threadIdx.x;
  if (e >= E) return;
  int i = eii[E+e];
  int p = atomicAdd(&cursor[i], 1);
  int k = rowptr[i] + p;
  jp[k] = eii[e];
  ip[k] = i;
}

// ---------------- geometry + RBF ----------------
__global__ void k_geom(const float* __restrict__ pos,
                       const int* __restrict__ jp, const int* __restrict__ ip,
                       int off, int Cc,
                       float* __restrict__ edb, float* __restrict__ ecv,
                       float* __restrict__ rb, ushortT* __restrict__ remb)
{
  int el = blockIdx.x*blockDim.x + threadIdx.x;
  if (el >= Cc) return;
  int g = off + el;
  int j = jp[g], i = ip[g];
  float pjx = pos[3*j], pjy = pos[3*j+1], pjz = pos[3*j+2];
  float pix = pos[3*i], piy = pos[3*i+1], piz = pos[3*i+2];
  float vx = pjx-pix, vy = pjy-piy, vz = pjz-piz;
  float d = sqrtf(vx*vx + vy*vy + vz*vz);
  float inv = RCPF(d + 1e-10f);
  float edx = vx*inv, edy = vy*inv, edz = vz*inv;
  edb[3*el]=edx; edb[3*el+1]=edy; edb[3*el+2]=edz;
  if (ecv){
    float cx = piy*pjz - piz*pjy;
    float cy = piz*pjx - pix*pjz;
    float cz = pix*pjy - piy*pjx;
    float cn = sqrtf(cx*cx + cy*cy + cz*cz);
    float inv2 = RCPF(cn + 1e-10f);
    cx *= inv2; cy *= inv2; cz *= inv2;
    ecv[6*el]=cx; ecv[6*el+1]=cy; ecv[6*el+2]=cz;
    ecv[6*el+3]=edy*cz - edz*cy;
    ecv[6*el+4]=edz*cx - edx*cz;
    ecv[6*el+5]=edx*cy - edy*cx;
  }
  float rbv = 0.5f*(COSR(d*0.08333333333f) + 1.f);   // cos(d*pi/6)
  rb[el] = rbv;
  float env = (d < 6.f) ? rbv : 0.f;
  const float stf = 0.0024787522f;
  const float prf = (2.0f/96.0f)*(1.0f - stf);
  const float betaL = LOG2E/(prf*prf);
  float emd = EXP2F(-LOG2E*d);
  for (int k = 0; k < NRAD; ++k){
    float mu = stf + (1.0f - stf)*((float)k*(1.0f/95.0f));
    float t = emd - mu;
    remb[(size_t)el*NRAD + k] = f2b(env * EXP2F(-betaL*t*t));
  }
}

// ---------------- fused rl MLP: rhid = rb * (silu(remb@W1+b1)@W2+b2) ----------------
// block = 64 edges, 256 threads (4 waves). remb stride 96, rhid stride 128.
__global__ __launch_bounds__(256) void k_rlmlp(
  const ushortT* __restrict__ remb, const ushortT* __restrict__ w1t,
  const float* __restrict__ b1, const ushortT* __restrict__ w2t,
  const float* __restrict__ b2, const float* __restrict__ rb,
  ushortT* __restrict__ rhid, int Cc)
{
  __shared__ ushortT sm[26112];           // 52.2 KB
  ushortT* sA  = sm;                      // 64 x 104 (96 used), stage 1
  ushortT* sW1 = sm + 6656;               // 128 x 104, stage 1
  ushortT* sA2 = sm;                      // 64 x 136 (128 used), stage 2
  ushortT* sW2 = sm + 8704;               // 128 x 136, stage 2
  const int tid = threadIdx.x;
  const int w = tid >> 6, lane = tid & 63;
  const int l15 = lane & 15, q = lane >> 4;
  const int eBase = blockIdx.x * 64;

  for (int i = tid; i < 64*12; i += 256){
    int r = i / 12, cb = (i % 12) << 3;
    int el = eBase + r; if (el >= Cc) el = Cc - 1;
    *(int4*)&sA[r*104 + cb] = *(const int4*)&remb[(size_t)el*96 + cb];
  }
  for (int i = tid; i < 128*12; i += 256){
    int r = i / 12, cb = (i % 12) << 3;
    *(int4*)&sW1[r*104 + cb] = *(const int4*)&w1t[(size_t)r*96 + cb];
  }
  __syncthreads();

  f4_t acc[4][2] = {};
  #pragma unroll
  for (int k0 = 0; k0 < 96; k0 += 32){
    bf8_t a[4], b[2];
    #pragma unroll
    for (int mt = 0; mt < 4; ++mt)
      a[mt] = *(const bf8_t*)&sA[(mt*16 + l15)*104 + k0 + q*8];
    #pragma unroll
    for (int nt = 0; nt < 2; ++nt)
      b[nt] = *(const bf8_t*)&sW1[(w*32 + nt*16 + l15)*104 + k0 + q*8];
    #pragma unroll
    for (int mt = 0; mt < 4; ++mt)
      #pragma unroll
      for (int nt = 0; nt < 2; ++nt)
        acc[mt][nt] = __builtin_amdgcn_mfma_f32_16x16x32_bf16(a[mt], b[nt], acc[mt][nt], 0, 0, 0);
  }
  __syncthreads();

  // silu -> sA2 (bf16); load W2
  #pragma unroll
  for (int mt = 0; mt < 4; ++mt){
    #pragma unroll
    for (int nt = 0; nt < 2; ++nt){
      int col = w*32 + nt*16 + l15;
      float bv = b1[col];
      #pragma unroll
      for (int r = 0; r < 4; ++r){
        int row = mt*16 + q*4 + r;
        sA2[row*136 + col] = f2b(silu_f(acc[mt][nt][r] + bv));
      }
    }
  }
  for (int i = tid; i < 128*16; i += 256){
    int r = i / 16, cb = (i % 16) << 3;
    *(int4*)&sW2[r*136 + cb] = *(const int4*)&w2t[(size_t)r*128 + cb];
  }
  __syncthreads();

  f4_t acc2[4][2] = {};
  #pragma unroll
  for (int k0 = 0; k0 < 128; k0 += 32){
    bf8_t a[4], b[2];
    #pragma unroll
    for (int mt = 0; mt < 4; ++mt)
      a[mt] = *(const bf8_t*)&sA2[(mt*16 + l15)*136 + k0 + q*8];
    #pragma unroll
    for (int nt = 0; nt < 2; ++nt)
      b[nt] = *(const bf8_t*)&sW2[(w*32 + nt*16 + l15)*136 + k0 + q*8];
    #pragma unroll
    for (int mt = 0; mt < 4; ++mt)
      #pragma unroll
      for (int nt = 0; nt < 2; ++nt)
        acc2[mt][nt] = __builtin_amdgcn_mfma_f32_16x16x32_bf16(a[mt], b[nt], acc2[mt][nt], 0, 0, 0);
  }
  #pragma unroll
  for (int mt = 0; mt < 4; ++mt){
    #pragma unroll
    for (int nt = 0; nt < 2; ++nt){
      int col = w*32 + nt*16 + l15;
      float bv = b2[col];
      #pragma unroll
      for (int r = 0; r < 4; ++r){
        int row = mt*16 + q*4 + r;
        int el = eBase + row;
        if (el < Cc)
          rhid[(size_t)el*128 + col] = f2b((acc2[mt][nt][r] + bv) * rb[el]);
      }
    }
  }
}

// ---------------- node embedding + layernorm (+ fused accumulator zeroing) ----------------
__global__ __launch_bounds__(128) void k_embed(const int* __restrict__ z,
    const float* __restrict__ ne_w, const float* __restrict__ ne_b,
    float* __restrict__ s, float* __restrict__ h0,
    float* __restrict__ S, float* __restrict__ vecacc)
{
  int n = blockIdx.x; int h = threadIdx.x;
  float x = ne_w[(size_t)z[n]*HIDDIM + h] + ne_b[h];
  __shared__ float red[128];
  red[h] = x; __syncthreads();
  for (int o = 64; o > 0; o >>= 1){ if (h < o) red[h] += red[h+o]; __syncthreads(); }
  float mean = red[0] * (1.f/128.f);
  __syncthreads();
  float dx = x - mean;
  red[h] = dx*dx; __syncthreads();
  for (int o = 64; o > 0; o >>= 1){ if (h < o) red[h] += red[h+o]; __syncthreads(); }
  float var = red[0] * (1.f/128.f);
  float y = dx * rsqrtf(var + 1e-5f);
  s[(size_t)n*HIDDIM + h] = y;
  h0[(size_t)n*HIDDIM + h] = y;
  float* Sr = &S[(size_t)n*384 + h];
  float* Vr = &vecacc[(size_t)n*384 + h];
  Sr[0]=0.f; Sr[128]=0.f; Sr[256]=0.f;
  Vr[0]=0.f; Vr[128]=0.f; Vr[256]=0.f;
}

// LN -> xln_b, plus fused s -> sb conversion
__global__ __launch_bounds__(128) void k_ln(const float* __restrict__ src, ushortT* __restrict__ dst,
    const float* __restrict__ g, const float* __restrict__ b, ushortT* __restrict__ sb)
{
  int n = blockIdx.x; int h = threadIdx.x;
  float x = src[(size_t)n*HIDDIM + h];
  sb[(size_t)n*HIDDIM + h] = f2b(x);
  __shared__ float red[128];
  red[h] = x; __syncthreads();
  for (int o = 64; o > 0; o >>= 1){ if (h < o) red[h] += red[h+o]; __syncthreads(); }
  float mean = red[0] * (1.f/128.f);
  __syncthreads();
  float dx = x - mean;
  red[h] = dx*dx; __syncthreads();
  for (int o = 64; o > 0; o >>= 1){ if (h < o) red[h] += red[h+o]; __syncthreads(); }
  float var = red[0] * (1.f/128.f);
  float y = dx * rsqrtf(var + 1e-5f);
  dst[(size_t)n*HIDDIM + h] = f2b(y * g[h] + b[h]);
}

// ---------------- rowptr-based segment sums (one block per node) ----------------
__global__ __launch_bounds__(128) void k_seg1n(const int* __restrict__ rowptr,
    const int* __restrict__ jp, int o, int Cc,
    const float* __restrict__ h0, const ushortT* __restrict__ rhid,
    float* __restrict__ s)
{
  int i = blockIdx.x, h = threadIdx.x;
  int b = rowptr[i], e = rowptr[i+1];
  if (b < o) b = o;
  int hi = o + Cc; if (e > hi) e = hi;
  if (b >= e) return;
  float acc = 0.f;
  int m = b;
  for (; m + 1 < e; m += 2){
    int j0 = jp[m], j1 = jp[m+1];
    float r0 = b2f(rhid[(size_t)(m-o)*HIDDIM + h]);
    float r1 = b2f(rhid[(size_t)(m+1-o)*HIDDIM + h]);
    acc += h0[(size_t)j0*HIDDIM + h]*r0 + h0[(size_t)j1*HIDDIM + h]*r1;
  }
  if (m < e) acc += h0[(size_t)jp[m]*HIDDIM + h] * b2f(rhid[(size_t)(m-o)*HIDDIM + h]);
  s[(size_t)i*HIDDIM + h] += acc;
}

__global__ __launch_bounds__(128) void k_seg2n(const int* __restrict__ rowptr,
    const int* __restrict__ jp, int o, int Cc,
    const ushortT* __restrict__ slin, const ushortT* __restrict__ rhid,
    const float* __restrict__ edb, float* __restrict__ S)
{
  int i = blockIdx.x, h = threadIdx.x;
  int b = rowptr[i], e = rowptr[i+1];
  if (b < o) b = o;
  int hi = o + Cc; if (e > hi) e = hi;
  if (b >= e) return;
  float a0 = 0.f, a1 = 0.f, a2 = 0.f;
  int m = b;
  for (; m + 1 < e; m += 2){
    int ml = m - o, ml2 = ml + 1;
    float u0 = b2f(slin[(size_t)jp[m]*HIDDIM + h])   * b2f(rhid[(size_t)ml*HIDDIM + h]);
    float u1 = b2f(slin[(size_t)jp[m+1]*HIDDIM + h]) * b2f(rhid[(size_t)ml2*HIDDIM + h]);
    a0 += u0*edb[3*ml]   + u1*edb[3*ml2];
    a1 += u0*edb[3*ml+1] + u1*edb[3*ml2+1];
    a2 += u0*edb[3*ml+2] + u1*edb[3*ml2+2];
  }
  if (m < e){
    int ml = m - o;
    float u0 = b2f(slin[(size_t)jp[m]*HIDDIM + h]) * b2f(rhid[(size_t)ml*HIDDIM + h]);
    a0 += u0*edb[3*ml]; a1 += u0*edb[3*ml+1]; a2 += u0*edb[3*ml+2];
  }
  float* base = &S[(size_t)i*384 + h];
  base[0]   += a0;
  base[128] += a1;
  base[256] += a2;
}

__global__ __launch_bounds__(128) void k_seg3n(const int* __restrict__ rowptr,
    int o, int Cc,
    const ushortT* __restrict__ mb, const float* __restrict__ edb,
    float* __restrict__ s, float* __restrict__ vecacc)
{
  int i = blockIdx.x, h = threadIdx.x;
  int b = rowptr[i], e = rowptr[i+1];
  if (b < o) b = o;
  int hi = o + Cc; if (e > hi) e = hi;
  if (b >= e) return;
  const float is128 = 0.08838834764831845f;
  float am = 0.f, v0 = 0.f, v1 = 0.f, v2 = 0.f;
  int m = b;
  for (; m + 1 < e; m += 2){
    int ml = m - o, ml2 = ml + 1;
    float m1a = b2f(mb[(size_t)ml*384 + h]);
    float m1b = b2f(mb[(size_t)ml2*384 + h]);
    float mma = b2f(mb[(size_t)ml*384 + 256 + h]) * is128;
    float mmb = b2f(mb[(size_t)ml2*384 + 256 + h]) * is128;
    am += m1a + m1b;
    v0 += mma*edb[3*ml]   + mmb*edb[3*ml2];
    v1 += mma*edb[3*ml+1] + mmb*edb[3*ml2+1];
    v2 += mma*edb[3*ml+2] + mmb*edb[3*ml2+2];
  }
  if (m < e){
    int ml = m - o;
    float m1 = b2f(mb[(size_t)ml*384 + h]);
    float mm = b2f(mb[(size_t)ml*384 + 256 + h]) * is128;
    am += m1;
    v0 += mm*edb[3*ml]; v1 += mm*edb[3*ml+1]; v2 += mm*edb[3*ml+2];
  }
  s[(size_t)i*HIDDIM + h] += am;
  float* base = &vecacc[(size_t)i*384 + h];
  base[0]   += v0;
  base[128] += v1;
  base[256] += v2;
}

// ---------------- scalarize v4: 2 edges/block, no LDS, scalar weights ----------------
__global__ __launch_bounds__(256) void k_scal4(
  const int* __restrict__ jp, const int* __restrict__ ip, int off, int Cc,
  const float* __restrict__ S,
  const float* __restrict__ edb, const float* __restrict__ ecv,
  const float* __restrict__ rb,
  const float* __restrict__ l3s,
  ushortT* __restrict__ ews)
{
  int ea = blockIdx.x*2;
  int eb = (ea + 1 < Cc) ? ea + 1 : ea;
  int t = threadIdx.x;
  int which = t >> 7, h = t & 127;
  int ga = off + ea, gb = off + eb;
  int na = which ? jp[ga] : ip[ga];
  int nb = which ? jp[gb] : ip[gb];
  f2_t f00 = {edb[3*ea],   edb[3*eb]};
  f2_t f01 = {edb[3*ea+1], edb[3*eb+1]};
  f2_t f02 = {edb[3*ea+2], edb[3*eb+2]};
  f2_t f10 = {ecv[6*ea],   ecv[6*eb]};
  f2_t f11 = {ecv[6*ea+1], ecv[6*eb+1]};
  f2_t f12 = {ecv[6*ea+2], ecv[6*eb+2]};
  f2_t f20 = {ecv[6*ea+3], ecv[6*eb+3]};
  f2_t f21 = {ecv[6*ea+4], ecv[6*eb+4]};
  f2_t f22 = {ecv[6*ea+5], ecv[6*eb+5]};
  f2_t rbv = {rb[ea], rb[eb]};
  const float* Sa = &S[(size_t)na*384];
  const float* Sb = &S[(size_t)nb*384];
  f2_t S0 = {Sa[h],     Sb[h]};
  f2_t S1 = {Sa[128+h], Sb[128+h]};
  f2_t S2 = {Sa[256+h], Sb[256+h]};
  f2_t v0 = S0*f00 + S1*f01 + S2*f02;
  f2_t v1t = S0*f10 + S1*f11 + S2*f12;
  f2_t v1 = {fabsf(v1t.x), fabsf(v1t.y)};
  f2_t v2 = S0*f20 + S1*f21 + S2*f22;
  f2_t out = {0.f, 0.f};
  #pragma unroll
  for (int u = 0; u < 32; ++u){
    f2_t tt = v0*l3s[u] + v1*l3s[32+u] + v2*l3s[64+u] + l3s[96+u];
    f2_t r;
    r.x = RCPF(1.f + EXP2F(tt.x));
    r.y = RCPF(1.f + EXP2F(tt.y));
    out += (tt*r)*l3s[128+u];
  }
  f2_t res = (out + l3s[160] + v0) * rbv;
  ews[(size_t)ea*256 + which*128 + h] = f2b(res.x);
  if (eb != ea) ews[(size_t)eb*256 + which*128 + h] = f2b(res.y);
}

// ---------------- bf16 MFMA GEMM ----------------
// A: MxK bf16 row-major; BT: NxK bf16 row-major. N%128==0, K%32==0.
// epi: 0 none, 1 silu, 2 *rowscale[row], 3 *mul1b[row,col]*xhpb[jidx[row],col]
// skipTile >= 0: that 128-col tile is not computed (grid.x one smaller).
// A1 != nullptr: split-A — K [0,256) from A (stride 256), [256,384) from A1
// (stride 128), [384,480) from A2 (stride 96).
__global__ __launch_bounds__(256) void mgemm(
  const ushortT* __restrict__ A, const ushortT* __restrict__ BT,
  const float* __restrict__ bias,
  float* __restrict__ Cf, ushortT* __restrict__ Cb,
  int M, int N, int K, int epi,
  const float* __restrict__ rowscale,
  const ushortT* __restrict__ mul1b,
  const ushortT* __restrict__ xhpb,
  const int* __restrict__ jidx,
  int skipTile,
  const ushortT* __restrict__ A1, const ushortT* __restrict__ A2)
{
  const int tid = threadIdx.x;
  const int w = tid >> 6;
  const int lane = tid & 63;
  const int l15 = lane & 15;
  const int q = lane >> 4;
  const int wm = w & 1, wn = w >> 1;
  const int rowBase = blockIdx.y * 128;
  int bx = blockIdx.x;
  if (skipTile >= 0 && bx >= skipTile) bx++;
  const int colBase = bx * 128;
  f4_t acc[4][4] = {};

#ifdef HAVE_GLDS
  __shared__ ushortT As[128*32];
  __shared__ ushortT Bs[128*32];
  const int rS = 32*w + (lane >> 2);
  const int kS = (lane & 3) << 3;
  ushortT* lA0 = &As[(32*w)*32];
  ushortT* lA1 = &As[(32*w+16)*32];
  ushortT* lB0 = &Bs[(32*w)*32];
  ushortT* lB1 = &Bs[(32*w+16)*32];
  int ra0 = rowBase + rS;      if (ra0 >= M) ra0 = M-1;
  int ra1 = rowBase + rS + 16; if (ra1 >= M) ra1 = M-1;
  const ushortT* gB0 = BT + (size_t)(colBase + rS)*K + kS;
  const ushortT* gB1 = BT + (size_t)(colBase + rS + 16)*K + kS;
  for (int k0 = 0; k0 < K; k0 += 32){
    const ushortT* srcA; size_t strA; int kc;
    if (!A1){ srcA = A; strA = (size_t)K; kc = k0; }
    else if (k0 < 256){ srcA = A; strA = 256; kc = k0; }
    else if (k0 < 384){ srcA = A1; strA = 128; kc = k0 - 256; }
    else { srcA = A2; strA = 96; kc = k0 - 384; }
    glds16(srcA + (size_t)ra0*strA + kc + kS, lA0);
    glds16(srcA + (size_t)ra1*strA + kc + kS, lA1);
    glds16(gB0 + k0, lB0);
    glds16(gB1 + k0, lB1);
    __syncthreads();
    bf8_t a[4], b[4];
    #pragma unroll
    for (int mt = 0; mt < 4; ++mt)
      a[mt] = *(const bf8_t*)&As[(wm*64 + mt*16 + l15)*32 + q*8];
    #pragma unroll
    for (int nt = 0; nt < 4; ++nt)
      b[nt] = *(const bf8_t*)&Bs[(wn*64 + nt*16 + l15)*32 + q*8];
    #pragma unroll
    for (int mt = 0; mt < 4; ++mt){
      #pragma unroll
      for (int nt = 0; nt < 4; ++nt)
        acc[mt][nt] = __builtin_amdgcn_mfma_f32_16x16x32_bf16(a[mt], b[nt], acc[mt][nt], 0, 0, 0);
    }
    __syncthreads();
  }
#else
  __shared__ ushortT As[128*48];
  __shared__ ushortT Bs[128*48];
  const int r0 = tid >> 2,         s0 = (tid & 3) << 3;
  const int r1 = (tid + 256) >> 2, s1 = ((tid + 256) & 3) << 3;
  for (int k0 = 0; k0 < K; k0 += 32){
    const ushortT* srcA; size_t strA; int kc;
    if (!A1){ srcA = A; strA = (size_t)K; kc = k0; }
    else if (k0 < 256){ srcA = A; strA = 256; kc = k0; }
    else if (k0 < 384){ srcA = A1; strA = 128; kc = k0 - 256; }
    else { srcA = A2; strA = 96; kc = k0 - 384; }
    int4 a0v = make_int4(0,0,0,0), a1v = make_int4(0,0,0,0);
    if (rowBase + r0 < M) a0v = *(const int4*)&srcA[(size_t)(rowBase + r0)*strA + kc + s0];
    if (rowBase + r1 < M) a1v = *(const int4*)&srcA[(size_t)(rowBase + r1)*strA + kc + s1];
    int4 b0v = *(const int4*)&BT[(size_t)(colBase + r0)*K + k0 + s0];
    int4 b1v = *(const int4*)&BT[(size_t)(colBase + r1)*K + k0 + s1];
    __syncthreads();
    *(int4*)&As[r0*48 + s0] = a0v;
    *(int4*)&As[r1*48 + s1] = a1v;
    *(int4*)&Bs[r0*48 + s0] = b0v;
    *(int4*)&Bs[r1*48 + s1] = b1v;
    __syncthreads();
    bf8_t a[4], b[4];
    #pragma unroll
    for (int mt = 0; mt < 4; ++mt)
      a[mt] = *(const bf8_t*)&As[(wm*64 + mt*16 + l15)*48 + q*8];
    #pragma unroll
    for (int nt = 0; nt < 4; ++nt)
      b[nt] = *(const bf8_t*)&Bs[(wn*64 + nt*16 + l15)*48 + q*8];
    #pragma unroll
    for (int mt = 0; mt < 4; ++mt){
      #pragma unroll
      for (int nt = 0; nt < 4; ++nt)
        acc[mt][nt] = __builtin_amdgcn_mfma_f32_16x16x32_bf16(a[mt], b[nt], acc[mt][nt], 0, 0, 0);
    }
  }
#endif

  #pragma unroll
  for (int mt = 0; mt < 4; ++mt){
    int row = rowBase + wm*64 + mt*16 + q*4;
    #pragma unroll
    for (int nt = 0; nt < 4; ++nt){
      int col = colBase + wn*64 + nt*16 + l15;
      float bv = bias ? bias[col] : 0.f;
      #pragma unroll
      for (int r = 0; r < 4; ++r){
        int rr = row + r;
        if (rr >= M) continue;
        float x = acc[mt][nt][r] + bv;
        if (epi == 1) x = silu_f(x);
        else if (epi == 2) x *= rowscale[rr];
        else if (epi == 3) x = x * b2f(mul1b[(size_t)rr*N + col]) * b2f(xhpb[(size_t)jidx[rr]*N + col]);
        if (Cb) Cb[(size_t)rr*N + col] = f2b(x);
        else    Cf[(size_t)rr*N + col] = x;
      }
    }
  }
}

// ---------------- fte prep ----------------
__global__ __launch_bounds__(128) void k_fte_pre(const float* __restrict__ vpc,
    const float* __restrict__ s, ushortT* __restrict__ catb, float* __restrict__ vdot,
    int no)
{
  int nl = blockIdx.x, h = threadIdx.x;
  int n = no + nl;
  const float* base = &vpc[(size_t)nl*768];
  float a0 = base[h],       a1 = base[256+h],     a2 = base[512+h];
  float c0 = base[128+h],   c1 = base[384+h],     c2 = base[640+h];
  float scal = sqrtf(a0*a0 + a1*a1 + a2*a2 + 1e-10f);
  float vd = (a0*c0 + a1*c1 + a2*c2) * 0.08838834764831845f;
  catb[(size_t)n*256 + h] = f2b(s[(size_t)n*HIDDIM + h]);
  catb[(size_t)n*256 + 128 + h] = f2b(scal);
  vdot[(size_t)n*HIDDIM + h] = vd;
}

// ---------------- final ----------------
__global__ __launch_bounds__(128) void k_out(const float* __restrict__ xh2,
    const float* __restrict__ vdot, const float* __restrict__ s,
    const float* __restrict__ ow, const float* __restrict__ ob,
    float* __restrict__ nodeout)
{
  int n = blockIdx.x, h = threadIdx.x;
  float a1 = xh2[(size_t)n*384 + h];
  float a2 = xh2[(size_t)n*384 + 128 + h];
  float sv = s[(size_t)n*HIDDIM + h] + (a1 + a2*vdot[(size_t)n*HIDDIM + h]) * 0.7071067811865476f;
  __shared__ float red[128];
  red[h] = sv * ow[h];
  __syncthreads();
  for (int o = 64; o > 0; o >>= 1){ if (h < o) red[h] += red[h+o]; __syncthreads(); }
  if (h == 0) nodeout[n] = red[0] + ob[0];
}

__global__ __launch_bounds__(256) void k_final(const float* __restrict__ nodeout,
    const int* __restrict__ batch, void* __restrict__ out, int Nn, const int* flags)
{
  int g = blockIdx.x;
  __shared__ float rs[256], rc[256];
  float sm = 0.f, c = 0.f;
  for (int n = threadIdx.x; n < Nn; n += 256){
    if (batch[n] == g){ sm += nodeout[n]; c += 1.f; }
  }
  rs[threadIdx.x] = sm; rc[threadIdx.x] = c;
  __syncthreads();
  for (int o = 128; o > 0; o >>= 1){
    if (threadIdx.x < o){ rs[threadIdx.x] += rs[threadIdx.x+o]; rc[threadIdx.x] += rc[threadIdx.x+o]; }
    __syncthreads();
  }
  if (threadIdx.x == 0){
    float v = (rc[0] > 0.f) ? rs[0]/rc[0] : 0.f;
    if (flags[2] == 0) ((__hip_bfloat16*)out)[g] = __float2bfloat16(v);
    else ((float*)out)[g] = v;
  }
}

// =====================================================================
extern "C" void kernel_launch(void* const* d_in, const int* in_sizes, int n_in,
                              void* d_out, int out_size, void* d_ws, size_t ws_size,
                              hipStream_t stream)
{
  const int N = in_sizes[0] / 3;
  const int E = in_sizes[3] / 2;

  size_t off = 0;
  auto alloc = [&](size_t n)->float*{
    float* p = (float*)d_ws + off;
    off += (n + 3) & ~(size_t)3;
    return p;
  };
  auto allocU = [&](size_t n)->ushortT*{ return (ushortT*)alloc((n + 1) / 2); };

  int* flags  = (int*)alloc(4);
  int* deg    = (int*)alloc((size_t)N);
  int* cursor = (int*)alloc((size_t)N);
  size_t zeroHdr = off;
  int* zi     = (int*)alloc((size_t)N);
  int* bi     = (int*)alloc((size_t)N);
  int* eii    = (int*)alloc((size_t)2*E);
  int* rowptr = (int*)alloc((size_t)N + 4);
  int* jp     = (int*)alloc((size_t)E);
  int* ipp    = (int*)alloc((size_t)E);
  float* l3s  = alloc(164);

  float* pos = alloc((size_t)N*3);
  float* w[31];
  for (int t = 0; t < 31; ++t) w[t] = alloc((size_t)in_sizes[4+t]);
  float* rl_b1=w[1];  float* rl_b2=w[3];
  float* ne_w =w[4];  float* ne_b =w[5];  float* sv_b =w[7];
  float* l3_w1=w[8];  float* l3_b1=w[9];  float* l3_w2=w[10]; float* l3_b2=w[11];
  float* mp_w =w[12]; float* mp_b =w[13]; float* xp_b1=w[15];
  float* xp_b2=w[17]; float* rp_b =w[19];
  float* ip_b1=w[21]; float* ip_b2=w[23];
  float* fte_b1=w[26];float* fte_b2=w[28];float* out_w=w[29]; float* out_b=w[30];

  ushortT* wt_rl1 = allocU(96*128);
  ushortT* wt_rl2 = allocU(128*128);
  ushortT* wt_sv  = allocU(128*128);
  ushortT* wt_xp1 = allocU(128*128);
  ushortT* wt_xp2 = allocU((size_t)128*384);
  ushortT* wt_rp  = allocU((size_t)96*384);
  ushortT* wt_ip1 = allocU((size_t)480*384);
  ushortT* wt_ip2 = allocU((size_t)384*384);
  ushortT* wt_feq = allocU((size_t)128*256);
  ushortT* wt_ft1 = allocU((size_t)256*128);
  ushortT* wt_ft2 = allocU((size_t)128*384);

  float* s    = alloc((size_t)N*HIDDIM);
  float* h0   = alloc((size_t)N*HIDDIM);      // -> vdot overlay after seg1
  ushortT* sb     = allocU((size_t)N*HIDDIM); // sb+slin_b contiguous -> catb overlay
  ushortT* slin_b = allocU((size_t)N*HIDDIM);
  ushortT* xln_b  = allocU((size_t)N*HIDDIM);
  ushortT* hb     = allocU((size_t)N*HIDDIM);
  float* S    = alloc((size_t)N*384);         // -> vab overlay in phase F
  float* vecacc = alloc((size_t)N*384);       // -> xh2 overlay after f2b
  ushortT* xh_b = allocU((size_t)N*384);
  float* nodeout = alloc((size_t)N);
  float* vdot = h0;
  ushortT* catb = sb;
  ushortT* vab = (ushortT*)S;
  float* xh2 = vecacc;

  size_t wsF = ws_size / sizeof(float);

  // tier selection:
  //  tier2: persist edb(3)+ecv(6)+rb(1)+remb(48)+rhid(64) = 122 f/edge; chunk 576 f/edge
  //  tier1: persist edb+rhid (67 f/edge);                  chunk 631 f/edge
  //  tier0: nothing persists;                              chunk 698 f/edge
  int tier = 0; size_t p = 698;
  if (off + 122ULL*(size_t)E + 16 + 256ULL*576 <= wsF){ tier = 2; p = 576; }
  else if (off + 67ULL*(size_t)E + 16 + 256ULL*631 <= wsF){ tier = 1; p = 631; }

  ushortT *rhid_a = nullptr, *remb_a = nullptr;
  float *edb_a = nullptr, *ecv_a = nullptr, *rb_a = nullptr;
  if (tier >= 1){
    rhid_a = allocU((size_t)E*128);
    edb_a  = alloc((size_t)3*E);
  }
  if (tier == 2){
    ecv_a  = alloc((size_t)6*E);
    rb_a   = alloc((size_t)E);
    remb_a = allocU((size_t)E*96);
  }
  size_t availF = (wsF > off) ? (wsF - off) : 0;
  if (availF < 256*p){
    k_sentinel<<<1, 64, 0, stream>>>((__hip_bfloat16*)d_out, out_size,
                                     (float)(double)(ws_size >> 20));
    return;
  }
  size_t Cs = availF / p; if (Cs > (size_t)E) Cs = E;
  int C = (int)(Cs & ~(size_t)15);
  if (C < 256) C = 256;

  float* scratch0 = (float*)d_ws + off;
  ushortT* remb_l = nullptr; float *ecv_l = nullptr, *rb_l = nullptr;
  if (tier <= 1){
    remb_l = allocU((size_t)C*96);   // 48C
    ecv_l  = alloc((size_t)6*C);
    rb_l   = alloc((size_t)C);
  }
  float* edb_l = nullptr; ushortT* rhid_l = nullptr;
  if (tier == 0){
    edb_l  = alloc((size_t)3*C);
    rhid_l = allocU((size_t)C*128);
  }
  ushortT* ewReg = allocU((size_t)C*384);     // 192C: ews (256/edge) then Rmb (384/edge)
  ushortT* R2b  = allocU((size_t)C*384);      // 192C
  ushortT* R1b  = allocU((size_t)C*384);      // 192C
  ushortT* ews  = ewReg;
  ushortT* Rmb  = ewReg;
  float* vpc = scratch0;
  size_t scratchF = (size_t)C*p;

  auto mg = [&](const ushortT* A, const ushortT* BT, const float* bias,
                float* Cf, ushortT* Cb, int M, int Nc, int K, int epi,
                const float* rowscale = nullptr, const ushortT* mul1b = nullptr,
                const ushortT* xhpb = nullptr, const int* jidx = nullptr,
                int skipTile = -1,
                const ushortT* A1 = nullptr, const ushortT* A2 = nullptr){
    dim3 grid(Nc/128 - (skipTile >= 0 ? 1 : 0), (M + 127)/128);
    mgemm<<<grid, 256, 0, stream>>>(A, BT, bias, Cf, Cb, M, Nc, K, epi,
                                    rowscale, mul1b, xhpb, jidx, skipTile, A1, A2);
  };

  // 0) zero header, detect dtypes, int-normalize (+deg histogram)
  k_zero<<<64, 256, 0, stream>>>((float*)flags, (int)zeroHdr);
  k_detect<<<64, 256, 0, stream>>>((const ushortT*)d_in[0], in_sizes[0],
                                   (const int*)d_in[2], in_sizes[2], flags);
  k_iconv<<<1024, 256, 0, stream>>>((const int*)d_in[1], (const int*)d_in[2],
                                    (const int*)d_in[3], zi, bi, eii, N, E, flags, deg);

  // 1) float conversions + transposed bf16 weights + l3 prescale
  ConvArgs ca;
  ca.d[0] = { (const ushortT*)d_in[0], pos, in_sizes[0] };
  for (int t = 0; t < 31; ++t)
    ca.d[1+t] = { (const ushortT*)d_in[4+t], w[t], in_sizes[4+t] };
  k_conv<<<dim3(32, 32), 256, 0, stream>>>(ca, 32, flags);
  k_l3pre<<<1, 192, 0, stream>>>(l3_w1, l3_b1, l3_w2, l3_b2, l3s);

  TArgs ta;
  ta.d[0]  = { (const ushortT*)d_in[4],  wt_rl1, 96, 128 };
  ta.d[1]  = { (const ushortT*)d_in[6],  wt_rl2, 128, 128 };
  ta.d[2]  = { (const ushortT*)d_in[10], wt_sv,  128, 128 };
  ta.d[3]  = { (const ushortT*)d_in[18], wt_xp1, 128, 128 };
  ta.d[4]  = { (const ushortT*)d_in[20], wt_xp2, 128, 384 };
  ta.d[5]  = { (const ushortT*)d_in[22], wt_rp,  96, 384 };
  ta.d[6]  = { (const ushortT*)d_in[24], wt_ip1, 480, 384 };
  ta.d[7]  = { (const ushortT*)d_in[26], wt_ip2, 384, 384 };
  ta.d[8]  = { (const ushortT*)d_in[28], wt_feq, 128, 256 };
  ta.d[9]  = { (const ushortT*)d_in[29], wt_ft1, 256, 128 };
  ta.d[10] = { (const ushortT*)d_in[31], wt_ft2, 128, 384 };
  k_wt<<<dim3(48, 11), 256, 0, stream>>>(ta, 11, flags);

  // 2) CSR scan + scatter
  k_csr_scan<<<1, 256, 0, stream>>>(deg, rowptr, N);
  k_csr_scatter<<<(E + 255)/256, 256, 0, stream>>>(eii, E, rowptr, cursor, jp, ipp);

  // 3) node embedding (+ S/vecacc zero fused)
  k_embed<<<N, 128, 0, stream>>>(zi, ne_w, ne_b, s, h0, S, vecacc);

  // pre-pass + Phase B
  if (tier == 2){
    k_geom<<<(E + 255)/256, 256, 0, stream>>>(pos, jp, ipp, 0, E,
                                              edb_a, ecv_a, rb_a, remb_a);
    k_rlmlp<<<(E + 63)/64, 256, 0, stream>>>(remb_a, wt_rl1, rl_b1, wt_rl2, rl_b2,
                                             rb_a, rhid_a, E);
    k_seg1n<<<N, 128, 0, stream>>>(rowptr, jp, 0, E, h0, rhid_a, s);
  } else if (tier == 1){
    for (int o = 0; o < E; o += C){
      int Cc = (E - o < C) ? (E - o) : C;
      k_geom<<<(Cc + 255)/256, 256, 0, stream>>>(pos, jp, ipp, o, Cc,
                                                 edb_a + (size_t)3*o, nullptr, rb_l, remb_l);
      k_rlmlp<<<(Cc + 63)/64, 256, 0, stream>>>(remb_l, wt_rl1, rl_b1, wt_rl2, rl_b2,
                                                rb_l, rhid_a + (size_t)o*128, Cc);
    }
    k_seg1n<<<N, 128, 0, stream>>>(rowptr, jp, 0, E, h0, rhid_a, s);
  } else {
    for (int o = 0; o < E; o += C){
      int Cc = (E - o < C) ? (E - o) : C;
      k_geom<<<(Cc + 255)/256, 256, 0, stream>>>(pos, jp, ipp, o, Cc,
                                                 edb_l, nullptr, rb_l, remb_l);
      k_rlmlp<<<(Cc + 63)/64, 256, 0, stream>>>(remb_l, wt_rl1, rl_b1, wt_rl2, rl_b2,
                                                rb_l, rhid_l, Cc);
      k_seg1n<<<N, 128, 0, stream>>>(rowptr, jp, o, Cc, h0, rhid_l, s);
    }
  }

  // Phase C: slin, xln(+sb), xh (xh cols 128-255 dead -> skip tile 1)
  k_ln<<<N, 128, 0, stream>>>(s, xln_b, mp_w, mp_b, sb);
  mg(sb, wt_sv, sv_b, nullptr, slin_b, N, 128, 128, 1);
  mg(xln_b, wt_xp1, xp_b1, nullptr, hb, N, 128, 128, 1);
  mg(hb, wt_xp2, xp_b2, nullptr, xh_b, N, 384, 128, 0, nullptr, nullptr, nullptr, nullptr, 1);

  // Phase D: seg2
  if (tier >= 1){
    k_seg2n<<<N, 128, 0, stream>>>(rowptr, jp, 0, E, slin_b, rhid_a, edb_a, S);
  } else {
    for (int o = 0; o < E; o += C){
      int Cc = (E - o < C) ? (E - o) : C;
      k_geom<<<(Cc + 255)/256, 256, 0, stream>>>(pos, jp, ipp, o, Cc,
                                                 edb_l, nullptr, rb_l, remb_l);
      k_rlmlp<<<(Cc + 63)/64, 256, 0, stream>>>(remb_l, wt_rl1, rl_b1, wt_rl2, rl_b2,
                                                rb_l, rhid_l, Cc);
      k_seg2n<<<N, 128, 0, stream>>>(rowptr, jp, o, Cc, slin_b, rhid_l, edb_l, S);
    }
  }

  // Phase E: per-edge big MLPs + seg3 (rp/ip2 skip dead middle tile; ip1 split-A)
  for (int o = 0; o < E; o += C){
    int Cc = (E - o < C) ? (E - o) : C;
    const ushortT *rhid_p, *remb_p;
    const float *edb_p, *ecv_p, *rb_p;
    if (tier == 2){
      rhid_p = rhid_a + (size_t)o*128;
      edb_p  = edb_a + (size_t)3*o;
      ecv_p  = ecv_a + (size_t)6*o;
      rb_p   = rb_a + o;
      remb_p = remb_a + (size_t)o*96;
    } else if (tier == 1){
      k_geom<<<(Cc + 255)/256, 256, 0, stream>>>(pos, jp, ipp, o, Cc,
                                                 edb_a + (size_t)3*o, ecv_l, rb_l, remb_l);
      rhid_p = rhid_a + (size_t)o*128;
      edb_p  = edb_a + (size_t)3*o;
      ecv_p  = ecv_l; rb_p = rb_l; remb_p = remb_l;
    } else {
      k_geom<<<(Cc + 255)/256, 256, 0, stream>>>(pos, jp, ipp, o, Cc,
                                                 edb_l, ecv_l, rb_l, remb_l);
      k_rlmlp<<<(Cc + 63)/64, 256, 0, stream>>>(remb_l, wt_rl1, rl_b1, wt_rl2, rl_b2,
                                                rb_l, rhid_l, Cc);
      rhid_p = rhid_l; edb_p = edb_l; ecv_p = ecv_l; rb_p = rb_l; remb_p = remb_l;
    }
    k_scal4<<<(Cc + 1)/2, 256, 0, stream>>>(jp, ipp, o, Cc, S,
                                            edb_p, ecv_p, rb_p, l3s, ews);
    mg(remb_p, wt_rp, rp_b, nullptr, R1b, Cc, 384, 96, 0,
       nullptr, nullptr, nullptr, nullptr, 1);
    mg(ews, wt_ip1, ip_b1, nullptr, R2b, Cc, 384, 480, 1,
       nullptr, nullptr, nullptr, nullptr, -1, rhid_p, remb_p);
    mg(R2b, wt_ip2, ip_b2, nullptr, Rmb, Cc, 384, 384, 3,
       nullptr, R1b, xh_b, jp + o, 1);
    k_seg3n<<<N, 128, 0, stream>>>(rowptr, o, Cc, Rmb, edb_p, s, vecacc);
  }

  // Phase F: fte
  k_f2b<<<1024, 256, 0, stream>>>(vecacc, vab, N*384);
  int Cn = (int)(scratchF / 768);
  if (Cn > N) Cn = N;
  for (int no = 0; no < N; no += Cn){
    int Cc = (N - no < Cn) ? (N - no) : Cn;
    mg(vab + (size_t)no*384, wt_feq, nullptr, vpc, nullptr, 3*Cc, 256, 128, 0);
    k_fte_pre<<<Cc, 128, 0, stream>>>(vpc, s, catb, vdot, no);
  }
  mg(catb, wt_ft1, fte_b1, nullptr, hb, N, 128, 256, 1);
  mg(hb, wt_ft2, fte_b2, xh2, nullptr, N, 384, 128, 0);

  // Phase G
  k_out<<<N, 128, 0, stream>>>(xh2, vdot, s, out_w, out_b, nodeout);
  k_final<<<out_size, 256, 0, stream>>>(nodeout, bi, d_out, N, flags);
}